// Round 16
// baseline (280.553 us; speedup 1.0000x reference)
//
#include <hip/hip_runtime.h>

typedef unsigned short u16;
typedef unsigned int   u32;

using bf16x8 = __attribute__((ext_vector_type(8))) __bf16;
using f32x4  = __attribute__((ext_vector_type(4))) float;

#define EPS 1e-5f

__device__ __forceinline__ u16 f2bf(float f) {
  u32 u = __float_as_uint(f);
  u32 r = (u + 0x7FFFu + ((u >> 16) & 1u)) >> 16;
  return (u16)r;
}
__device__ __forceinline__ float bf2f(u16 h) {
  return __uint_as_float(((u32)h) << 16);
}

__device__ __forceinline__ void gload16(const void* g, void* l) {
  __builtin_amdgcn_global_load_lds((__attribute__((address_space(1))) void*)(void*)g,
                                   (__attribute__((address_space(3))) void*)l,
                                   16, 0, 0);
}

// 2-value block reduction (sum), blockDim in {256,512}; sm >= 2*(blockDim/64)
__device__ __forceinline__ void blockReduce2(float& a, float& b, float* sm) {
  #pragma unroll
  for (int off = 32; off > 0; off >>= 1) {
    a += __shfl_down(a, off);
    b += __shfl_down(b, off);
  }
  const int w = threadIdx.x >> 6, l = threadIdx.x & 63;
  const int nw = blockDim.x >> 6;
  __syncthreads();
  if (l == 0) { sm[2*w] = a; sm[2*w+1] = b; }
  __syncthreads();
  a = sm[0]; b = sm[1];
  for (int i = 1; i < nw; ++i) { a += sm[2*i]; b += sm[2*i+1]; }
}

// 2-value full-wave (64 lane) shuffle reduction
__device__ __forceinline__ void red64_2(float& a, float& b) {
  #pragma unroll
  for (int m = 1; m <= 32; m <<= 1) { a += __shfl_xor(a, m); b += __shfl_xor(b, m); }
}

// ---- K1: fused prep. blocks 0..2047: conv_w f32 [O][I][K] -> wt bf16 [O][K][I];
// block 2048: recurrent vectors; blocks 2049..6396: LN(x) -> xpad (+pad zeroing).
__global__ void k_prep(const float* __restrict__ cw, u16* __restrict__ wt,
                       const float* __restrict__ rwi, const float* __restrict__ rwf,
                       const float* __restrict__ rwo, const float* __restrict__ rwz,
                       const float* __restrict__ ht1, float* __restrict__ rv,
                       const float* __restrict__ x, const float* __restrict__ g,
                       const float* __restrict__ bta, u16* __restrict__ xpad) {
  __shared__ float tile[128][65];
  const int bid = blockIdx.x;
  const int tid = threadIdx.x;
  if (bid < 2048) {
    const int o  = bid >> 2;
    const int i0 = (bid & 3) << 7;
    const size_t inBase = ((size_t)(o*512 + i0)) << 6;
    for (int idx = tid; idx < 128*64; idx += 256) {
      const int ii = idx >> 6, k = idx & 63;
      tile[ii][k] = cw[inBase + ((size_t)ii << 6) + k];
    }
    __syncthreads();
    const size_t outBase = ((size_t)o << 15) + i0;
    for (int idx = tid; idx < 128*64; idx += 256) {
      const int k = idx >> 7, ii = idx & 127;
      wt[outBase + ((size_t)k << 9) + ii] = f2bf(tile[ii][k]);
    }
    return;
  }
  if (bid == 2048) {
    const float* w[4] = {rwi, rwf, rwo, rwz};
    for (int gg = 0; gg < 4; ++gg)
      for (int e = tid; e < 512; e += 256) {
        const float* wr = w[gg] + e*64;
        const float* hv = ht1 + (e >> 6)*64;
        float s = 0.f;
        for (int i = 0; i < 64; ++i) s = fmaf(wr[i], hv[i], s);
        rv[gg*512 + e] = s;
      }
    return;
  }
  const int row = bid - 2049;   // 0..4347
  if (row >= 4096) {
    const int idx = row - 4096;           // 0..251
    const int b = idx / 63, rr = idx % 63;
    const size_t base = ((size_t)(b*1087 + rr)) << 9;
    xpad[base + tid] = 0;
    xpad[base + tid + 256] = 0;
    return;
  }
  const int e0 = tid, e1 = tid + 256;
  const size_t ib = (size_t)row << 9;
  const float v0 = x[ib + e0], v1 = x[ib + e1];
  float a = v0 + v1, b2 = v0*v0 + v1*v1;
  blockReduce2(a, b2, (float*)tile);
  const float mu = a * (1.f/512.f);
  const float var = b2 * (1.f/512.f) - mu*mu;
  const float rs = rsqrtf(var + EPS);
  const int bb = row >> 10, t = row & 1023;
  const size_t ob = ((size_t)(bb*1087 + 63 + t)) << 9;
  xpad[ob + e0] = f2bf((v0 - mu) * rs * g[e0] + bta[e0]);
  xpad[ob + e1] = f2bf((v1 - mu) * rs * g[e1] + bta[e1]);
}

// ---- K3: conv-as-GEMM, 256x256 tile, BK=64, split-K=8, bf16 partials.
// R12-proven barrier-minimal tile schedule (unchanged).
__global__ __launch_bounds__(512) void k_gemm256(
    const u16* __restrict__ wt, const u16* __restrict__ xpad,
    u16* __restrict__ part, int kSteps)
{
  extern __shared__ __align__(16) char smem[];   // 2 x 65536
  const int tid  = threadIdx.x;
  const int lane = tid & 63;
  const int wid  = tid >> 6;
  const int wm = wid >> 2, wn = wid & 3;          // 2M x 4N waves, 128x64 out each
  const int mb = blockIdx.x, nb = blockIdx.y, sp = blockIdx.z;

  const int wmBase = wm * 128;
  const int wnBase = wn * 64;
  const int l15  = lane & 15;
  const int kb16 = (lane >> 4) << 4;

  const int srow = tid >> 3;
  const int scb  = (tid & 7) << 4;
  const int csrcE = (scb ^ ((srow & 7) << 4)) >> 1;   // pre-swizzled source col

  const u16* aB0;
  {
    const int m0 = mb*256 + srow;          // 256-chunks never cross a batch boundary
    const int b = m0 >> 10, t = m0 & 1023;
    aB0 = xpad + (((size_t)(b*1087 + t)) << 9) + csrcE;   // NO +63 (R8 bug)
  }
  const u16* bB0 = wt + (((size_t)(nb*256 + srow)) << 15) + csrcE;
  const size_t dst16 = (size_t)tid * 16;

  f32x4 acc[8][4];
  const f32x4 zero4 = {0.f, 0.f, 0.f, 0.f};
  #pragma unroll
  for (int i = 0; i < 8; ++i)
    #pragma unroll
    for (int j = 0; j < 4; ++j) acc[i][j] = zero4;

  const int kBase = sp * kSteps;

  auto STAGE = [&](int ktg, char* buf) {
    const size_t aOff = ((size_t)(ktg >> 3) << 9) + ((size_t)(ktg & 7) << 6);
    const size_t bOff = (size_t)ktg << 6;
    gload16(aB0 + aOff,                  buf + dst16);
    gload16(aB0 + (64ull << 9) + aOff,   buf +  8192 + dst16);
    gload16(aB0 + (128ull << 9) + aOff,  buf + 16384 + dst16);
    gload16(aB0 + (192ull << 9) + aOff,  buf + 24576 + dst16);
    gload16(bB0 + bOff,                   buf + 32768 + dst16);
    gload16(bB0 + (64ull << 15) + bOff,   buf + 40960 + dst16);
    gload16(bB0 + (128ull << 15) + bOff,  buf + 49152 + dst16);
    gload16(bB0 + (192ull << 15) + bOff,  buf + 57344 + dst16);
  };

  STAGE(kBase, smem);
  __syncthreads();

  for (int kt = 0; kt < kSteps; ++kt) {
    const char* curA = smem + (size_t)(kt & 1) * 65536;
    const char* curB = curA + 32768;
    char* nxt = smem + (size_t)((kt & 1) ^ 1) * 65536;
    if (kt + 1 < kSteps) STAGE(kBase + kt + 1, nxt);

    bf16x8 bv[4][2];
    #pragma unroll
    for (int nr = 0; nr < 4; ++nr) {
      const int r = wnBase + nr*16 + l15;
      const int sw = (r & 7) << 4;
      bv[nr][0] = *(const bf16x8*)(curB + r*128 + ((kb16     ) ^ sw));
      bv[nr][1] = *(const bf16x8*)(curB + r*128 + ((kb16 + 64) ^ sw));
    }
    #pragma unroll
    for (int q = 0; q < 4; ++q) {
      bf16x8 af0, af0b, af1, af1b;
      { const int r = wmBase + q*32 + l15; const int sw = (r & 7) << 4;
        af0  = *(const bf16x8*)(curA + r*128 + ((kb16     ) ^ sw));
        af0b = *(const bf16x8*)(curA + r*128 + ((kb16 + 64) ^ sw)); }
      { const int r = wmBase + q*32 + 16 + l15; const int sw = (r & 7) << 4;
        af1  = *(const bf16x8*)(curA + r*128 + ((kb16     ) ^ sw));
        af1b = *(const bf16x8*)(curA + r*128 + ((kb16 + 64) ^ sw)); }
      #pragma unroll
      for (int nr = 0; nr < 4; ++nr) {
        acc[2*q][nr]   = __builtin_amdgcn_mfma_f32_16x16x32_bf16(af0,  bv[nr][0], acc[2*q][nr],   0, 0, 0);
        acc[2*q][nr]   = __builtin_amdgcn_mfma_f32_16x16x32_bf16(af0b, bv[nr][1], acc[2*q][nr],   0, 0, 0);
        acc[2*q+1][nr] = __builtin_amdgcn_mfma_f32_16x16x32_bf16(af1,  bv[nr][0], acc[2*q+1][nr], 0, 0, 0);
        acc[2*q+1][nr] = __builtin_amdgcn_mfma_f32_16x16x32_bf16(af1b, bv[nr][1], acc[2*q+1][nr], 0, 0, 0);
      }
    }
    __syncthreads();
  }

  u16* outp = part + (size_t)sp * 4096 * 512;
  #pragma unroll
  for (int mr = 0; mr < 8; ++mr)
    #pragma unroll
    for (int nr = 0; nr < 4; ++nr)
      #pragma unroll
      for (int r4 = 0; r4 < 4; ++r4) {
        const int row = mb*256 + wmBase + mr*16 + ((lane >> 4) << 2) + r4;
        const int col = nb*256 + wnBase + nr*16 + l15;
        outp[((size_t)row << 9) + col] = f2bf(acc[mr][nr][r4]);
      }
}

// ---- K3 (fallback): R10-proven 128x128 tile, static 32KB LDS (bf16 partials).
__global__ __launch_bounds__(512) void k_gemm128(
    const u16* __restrict__ wt, const u16* __restrict__ xpad,
    u16* __restrict__ part, int kSteps)
{
  __shared__ __align__(16) u16 lsA[128*64];
  __shared__ __align__(16) u16 lsB[128*64];
  const int tid  = threadIdx.x;
  const int lane = tid & 63;
  const int wid  = tid >> 6;
  const int wm = wid >> 2, wn = wid & 3;
  const int mb = blockIdx.x, nb = blockIdx.y, sp = blockIdx.z;

  const int srow = tid >> 3;
  const int scb  = (tid & 7) << 4;
  const int csrcE = (scb ^ ((srow & 7) << 4)) >> 1;

  const int m0 = mb*128 + srow, m1 = m0 + 64;
  const int b0 = m0 >> 10, t0 = m0 & 1023;
  const int b1 = m1 >> 10, t1 = m1 & 1023;
  const u16* aB0 = xpad + (((size_t)(b0*1087 + t0)) << 9) + csrcE;
  const u16* aB1 = xpad + (((size_t)(b1*1087 + t1)) << 9) + csrcE;
  const u16* bB0 = wt + (((size_t)(nb*128 + srow)) << 15) + csrcE;
  const u16* bB1 = wt + (((size_t)(nb*128 + srow + 64)) << 15) + csrcE;
  u16* dA0 = &lsA[tid*8]; u16* dA1 = &lsA[4096 + tid*8];
  u16* dB0 = &lsB[tid*8]; u16* dB1 = &lsB[4096 + tid*8];

  const f32x4 zero4 = {0.f, 0.f, 0.f, 0.f};
  f32x4 acc[4][2];
  #pragma unroll
  for (int i = 0; i < 4; ++i)
    #pragma unroll
    for (int j = 0; j < 2; ++j) acc[i][j] = zero4;

  const int kBase = sp * kSteps;
  for (int kt = 0; kt < kSteps; ++kt) {
    const int ktg = kBase + kt;
    const int k  = ktg >> 3;
    const int i0 = (ktg & 7) << 6;
    const int aStep = (k << 9) + i0;
    gload16(aB0 + aStep, dA0);
    gload16(aB1 + aStep, dA1);
    gload16(bB0 + ((size_t)ktg << 6), dB0);
    gload16(bB1 + ((size_t)ktg << 6), dB1);
    __syncthreads();
    #pragma unroll
    for (int ks = 0; ks < 2; ++ks) {
      bf16x8 af[4], bv[2];
      #pragma unroll
      for (int mr = 0; mr < 4; ++mr) {
        const int r  = wm*64 + mr*16 + (lane & 15);
        const int cb = (ks << 6) + ((lane >> 4) << 4);
        af[mr] = *(const bf16x8*)((const char*)lsA + (r*128 + (cb ^ ((r & 7) << 4))));
      }
      #pragma unroll
      for (int nr = 0; nr < 2; ++nr) {
        const int r  = wn*32 + nr*16 + (lane & 15);
        const int cb = (ks << 6) + ((lane >> 4) << 4);
        bv[nr] = *(const bf16x8*)((const char*)lsB + (r*128 + (cb ^ ((r & 7) << 4))));
      }
      #pragma unroll
      for (int mr = 0; mr < 4; ++mr)
        #pragma unroll
        for (int nr = 0; nr < 2; ++nr)
          acc[mr][nr] = __builtin_amdgcn_mfma_f32_16x16x32_bf16(af[mr], bv[nr], acc[mr][nr], 0, 0, 0);
    }
    __syncthreads();
  }

  u16* outp = part + (size_t)sp * 4096 * 512;
  #pragma unroll
  for (int mr = 0; mr < 4; ++mr)
    #pragma unroll
    for (int nr = 0; nr < 2; ++nr)
      #pragma unroll
      for (int r4 = 0; r4 < 4; ++r4) {
        const int row = mb*128 + wm*64 + mr*16 + ((lane >> 4) << 2) + r4;
        const int col = nb*128 + wn*32 + nr*16 + (lane & 15);
        outp[((size_t)row << 9) + col] = f2bf(acc[mr][nr][r4]);
      }
}

// ---- K5: fused fp32 block-diag gates + LNs + gating + ct/nt partials.
// 512 blocks x 8 rows, ~70KB LDS -> 2 blocks/CU.
__global__ __launch_bounds__(512, 2) void k_bdg3(
    const u16* __restrict__ part, int S,
    const float* __restrict__ cb, const u16* __restrict__ xpad,
    const float* __restrict__ wi, const float* __restrict__ wf,
    const float* __restrict__ wo, const float* __restrict__ wz,
    const float* __restrict__ bi, const float* __restrict__ bf_,
    const float* __restrict__ bo, const float* __restrict__ bz,
    const float* __restrict__ rv,
    const float* __restrict__ lnig, const float* __restrict__ lnib,
    const float* __restrict__ lnfg, const float* __restrict__ lnfb,
    const float* __restrict__ lnog, const float* __restrict__ lnob,
    const float* __restrict__ lnzg, const float* __restrict__ lnzb,
    const float* __restrict__ lncg, const float* __restrict__ lncb,
    const float* __restrict__ lnng, const float* __restrict__ lnnb,
    const float* __restrict__ mt1, const float* __restrict__ ct1,
    const float* __restrict__ nt1,
    float* __restrict__ obuf, float* __restrict__ pct, float* __restrict__ pnt)
{
  extern __shared__ char smem2[];
  float* pre4 = (float*)smem2;                 // [4][8][512] f32 = 65536 B
  float* xsc  = (float*)(smem2 + 65536);       // [8][68]
  float* xsl  = xsc + 8*68;                    // [8][68]  (total +4352 B)
  float* pctW = pre4;                          // [8][512] phase-2 reuse
  float* pntW = pre4 + 8*512;

  const int tid  = threadIdx.x;
  const int lane = tid & 63;
  const int w    = tid >> 6;
  const int g    = w >> 1;           // gate 0..3
  const int rh   = w & 1;            // row half: rows rh*4 .. rh*4+3
  const int rowBase = blockIdx.x * 8;
  const size_t N = 4096ull*512;
  const float* wptr[4] = {wi, wf, wo, wz};
  const float* bptr[4] = {bi, bf_, bo, bz};
  const float* wg = wptr[g];
  const float* bg = bptr[g];

  const int sr    = (tid >> 5) & 7;    // staging row 0..7 (tid<256 active)
  const int scol2 = (tid & 31) << 1;   // staging col pair

  for (int d = 0; d < 8; ++d) {
    __syncthreads();
    if (tid < 256) {
      const int row = rowBase + sr, col = d*64 + scol2;
      float v0 = cb[col], v1 = cb[col+1];
      for (int s = 0; s < S; ++s) {
        const u32 p = *(const u32*)&part[(size_t)s*N + (size_t)row*512 + col];
        v0 += bf2f((u16)p);
        v1 += bf2f((u16)(p >> 16));
      }
      xsc[sr*68 + scol2]     = v0 / (1.f + expf(-v0));
      xsc[sr*68 + scol2 + 1] = v1 / (1.f + expf(-v1));
      const int bq = row >> 10, tt = row & 1023;
      const u32 xp = *(const u32*)&xpad[(((size_t)(bq*1087 + 63 + tt)) << 9) + col];
      xsl[sr*68 + scol2]     = bf2f((u16)xp);
      xsl[sr*68 + scol2 + 1] = bf2f((u16)(xp >> 16));
    }
    float4 wreg[16];
    {
      const float* wb = wg + (size_t)d*4096 + lane*64;
      #pragma unroll
      for (int j = 0; j < 16; ++j) wreg[j] = *(const float4*)(wb + 4*j);
    }
    __syncthreads();

    const float* X = (g < 2) ? xsc : xsl;
    float acc[4];
    #pragma unroll
    for (int r4 = 0; r4 < 4; ++r4) acc[r4] = 0.f;
    #pragma unroll
    for (int i4 = 0; i4 < 16; ++i4) {
      const float4 wv = wreg[i4];
      #pragma unroll
      for (int r4 = 0; r4 < 4; ++r4) {
        const float4 xv = *(const float4*)(X + (rh*4 + r4)*68 + (i4 << 2));
        acc[r4] = fmaf(xv.w, wv.w, fmaf(xv.z, wv.z, fmaf(xv.y, wv.y, fmaf(xv.x, wv.x, acc[r4]))));
      }
    }
    const int e = d*64 + lane;
    const float bias = bg[e] + rv[g*512 + e];
    #pragma unroll
    for (int r4 = 0; r4 < 4; ++r4)
      pre4[(g*8 + rh*4 + r4)*512 + e] = acc[r4] + bias;
  }
  __syncthreads();

  // ---- phase 2: wave w owns row w (8 waves, 8 rows)
  const int prow = w;
  const int grow = rowBase + prow;
  float gi[8], gf[8], go_[8], gz[8];
  #pragma unroll
  for (int j = 0; j < 8; ++j) {
    const int c = lane + 64*j;
    gi[j]  = pre4[(0*8 + prow)*512 + c];
    gf[j]  = pre4[(1*8 + prow)*512 + c];
    go_[j] = pre4[(2*8 + prow)*512 + c];
    gz[j]  = pre4[(3*8 + prow)*512 + c];
  }
  float si=0,si2=0,sf=0,sf2=0,so=0,so2=0,sz=0,sz2=0;
  #pragma unroll
  for (int j = 0; j < 8; ++j) {
    si += gi[j];  si2 += gi[j]*gi[j];
    sf += gf[j];  sf2 += gf[j]*gf[j];
    so += go_[j]; so2 += go_[j]*go_[j];
    sz += gz[j];  sz2 += gz[j]*gz[j];
  }
  red64_2(si, si2); red64_2(sf, sf2); red64_2(so, so2); red64_2(sz, sz2);
  const float mui = si*(1.f/512.f), rsi = rsqrtf(si2*(1.f/512.f) - mui*mui + EPS);
  const float muf = sf*(1.f/512.f), rsf = rsqrtf(sf2*(1.f/512.f) - muf*muf + EPS);
  const float muo = so*(1.f/512.f), rso = rsqrtf(so2*(1.f/512.f) - muo*muo + EPS);
  const float muz = sz*(1.f/512.f), rsz = rsqrtf(sz2*(1.f/512.f) - muz*muz + EPS);

  float ctv[8], ntv[8];
  float cS=0,cS2=0,nS=0,nS2=0;
  #pragma unroll
  for (int j = 0; j < 8; ++j) {
    const int c = lane + 64*j;
    const float li = (gi[j]-mui)*rsi*lnig[c] + lnib[c];
    const float lf = (gf[j]-muf)*rsf*lnfg[c] + lnfb[c];
    const float ov = 1.f/(1.f+expf(-((go_[j]-muo)*rso*lnog[c] + lnob[c])));
    const float zv = tanhf((gz[j]-muz)*rsz*lnzg[c] + lnzb[c]);
    obuf[(size_t)grow*512 + c] = ov;
    const float lfm = lf + mt1[c];
    const float mm = fmaxf(lfm, li);
    const float iv = expf(li - mm), fv = expf(lfm - mm);
    ctv[j] = fv*ct1[c] + iv*zv;
    ntv[j] = fv*nt1[c] + iv;
    cS += ctv[j]; cS2 += ctv[j]*ctv[j];
    nS += ntv[j]; nS2 += ntv[j]*ntv[j];
  }
  red64_2(cS, cS2); red64_2(nS, nS2);
  const float muc = cS*(1.f/512.f), rsc = rsqrtf(cS2*(1.f/512.f) - muc*muc + EPS);
  const float mun = nS*(1.f/512.f), rsn = rsqrtf(nS2*(1.f/512.f) - mun*mun + EPS);
  float pcA[8], pnA[8];
  #pragma unroll
  for (int j = 0; j < 8; ++j) {
    const int c = lane + 64*j;
    pcA[j] = (ctv[j]-muc)*rsc*lncg[c] + lncb[c];
    pnA[j] = (ntv[j]-mun)*rsn*lnng[c] + lnnb[c];
  }
  __syncthreads();   // all pre4 reads complete before reuse
  #pragma unroll
  for (int j = 0; j < 8; ++j) {
    const int c = lane + 64*j;
    pctW[w*512 + c] = pcA[j];
    pntW[w*512 + c] = pnA[j];
  }
  __syncthreads();
  {
    const int e = tid;
    float cs = 0.f, ns = 0.f;
    #pragma unroll
    for (int ww = 0; ww < 8; ++ww) { cs += pctW[ww*512 + e]; ns += pntW[ww*512 + e]; }
    pct[(size_t)blockIdx.x*512 + e] = cs;
    pnt[(size_t)blockIdx.x*512 + e] = ns;
  }
}

// ---- K5b: r[e] = sum_b(pct)/sum_b(pnt) over 512 partials; 512 blocks x 256 thr
__global__ void k_r(const float* __restrict__ pct, const float* __restrict__ pnt,
                    float* __restrict__ rout) {
  __shared__ float sm[8];
  const int e = blockIdx.x, tid = threadIdx.x;
  float cs = pct[(size_t)tid*512 + e] + pct[(size_t)(tid+256)*512 + e];
  float ns = pnt[(size_t)tid*512 + e] + pnt[(size_t)(tid+256)*512 + e];
  blockReduce2(cs, ns, sm);
  if (tid == 0) rout[e] = cs / ns;
}

// ---- K6: ht-row LN accumulation, wave-per-row (256 blocks x 16 rows)
__global__ __launch_bounds__(256) void k_ht(
    const float* __restrict__ obuf, const float* __restrict__ r,
    const float* __restrict__ lnhg, const float* __restrict__ lnhb,
    float* __restrict__ phtPart)
{
  __shared__ float rsh[512];
  __shared__ float phtW[4][512];
  const int tid = threadIdx.x, lane = tid & 63, w = tid >> 6;
  rsh[tid] = r[tid]; rsh[tid + 256] = r[tid + 256];
  __syncthreads();
  float accH[8] = {0,0,0,0,0,0,0,0};
  const int rowBase = blockIdx.x * 16;
  for (int rr = 0; rr < 4; ++rr) {
    const int row = rowBase + w*4 + rr;
    float v[8], s = 0.f, s2 = 0.f;
    #pragma unroll
    for (int j = 0; j < 8; ++j) {
      const int c = lane + 64*j;
      v[j] = obuf[(size_t)row*512 + c] * rsh[c];
      s += v[j]; s2 += v[j]*v[j];
    }
    #pragma unroll
    for (int m = 1; m <= 32; m <<= 1) { s += __shfl_xor(s, m); s2 += __shfl_xor(s2, m); }
    const float mu = s*(1.f/512.f), rs = rsqrtf(s2*(1.f/512.f) - mu*mu + EPS);
    #pragma unroll
    for (int j = 0; j < 8; ++j) {
      const int c = lane + 64*j;
      accH[j] += (v[j]-mu)*rs*lnhg[c] + lnhb[c];
    }
  }
  #pragma unroll
  for (int j = 0; j < 8; ++j) phtW[w][lane + 64*j] = accH[j];
  __syncthreads();
  const int e0 = tid, e1 = tid + 256;
  float h0 = 0.f, h1 = 0.f;
  #pragma unroll
  for (int ww = 0; ww < 4; ++ww) { h0 += phtW[ww][e0]; h1 += phtW[ww][e1]; }
  phtPart[(size_t)blockIdx.x*512 + e0] = h0;
  phtPart[(size_t)blockIdx.x*512 + e1] = h1;
}

// ---- K6b: htm[e] = (sum_b pht[b][e]) / 4096; 512 blocks x 256 thr
__global__ void k_hm(const float* __restrict__ pht, float* __restrict__ hm) {
  __shared__ float sm[8];
  const int e = blockIdx.x, tid = threadIdx.x;
  float v = pht[(size_t)tid*512 + e];
  float d = 0.f;
  blockReduce2(v, d, sm);
  if (tid == 0) hm[e] = v * (1.f/4096.f);
}

// ---- K7: fused gn-LN + left/right GEMV + gelu; 682 blocks x 64.
__global__ void k_lr2(const float* __restrict__ hm,
                      const float* __restrict__ gng, const float* __restrict__ gnb,
                      const float* __restrict__ lw, const float* __restrict__ lb,
                      const float* __restrict__ rw, const float* __restrict__ rb_,
                      float* __restrict__ lr) {
  const int j = blockIdx.x, lane = threadIdx.x;
  float h[8];
  float a = 0.f, b2 = 0.f;
  #pragma unroll
  for (int q = 0; q < 8; ++q) {
    h[q] = hm[lane + 64*q];
    a += h[q]; b2 += h[q]*h[q];
  }
  red64_2(a, b2);
  const float mu = a*(1.f/512.f), rs = rsqrtf(b2*(1.f/512.f) - mu*mu + EPS);
  const float* lwp = lw + (size_t)j*512;
  const float* rwp = rw + (size_t)j*512;
  float dl = 0.f, dr = 0.f;
  #pragma unroll
  for (int q = 0; q < 8; ++q) {
    const int e = lane + 64*q;
    const float sv = (h[q]-mu)*rs*gng[e] + gnb[e];
    dl = fmaf(lwp[e], sv, dl);
    dr = fmaf(rwp[e], sv, dr);
  }
  #pragma unroll
  for (int off = 32; off > 0; off >>= 1) { dl += __shfl_down(dl, off); dr += __shfl_down(dr, off); }
  if (lane == 0) {
    const float L = dl + lb[j];
    const float R = dr + rb_[j];
    const float gelu = 0.5f*R*(1.f + erff(R*0.70710678118654752440f));
    lr[j] = L * gelu;
  }
}

// ---- K8: fused LN(lr) + proj: 512 blocks x 64 lanes
__global__ void k_projln(const float* __restrict__ lr,
                         const float* __restrict__ og, const float* __restrict__ ob,
                         const float* __restrict__ pw, const float* __restrict__ pb,
                         float* __restrict__ out) {
  const int e = blockIdx.x, lane = threadIdx.x;
  float lv[11];
  float a = 0.f, b2 = 0.f;
  #pragma unroll
  for (int q = 0; q < 11; ++q) {
    const int j = lane + 64*q;
    const float v = (j < 682) ? lr[j] : 0.f;
    lv[q] = v;
    a += v; b2 += v*v;
  }
  red64_2(a, b2);
  const float mu = a*(1.f/682.f), rs = rsqrtf(b2*(1.f/682.f) - mu*mu + EPS);
  const float* wp = pw + (size_t)e*682;
  float s = 0.f;
  #pragma unroll
  for (int q = 0; q < 11; ++q) {
    const int j = lane + 64*q;
    if (j < 682) s = fmaf((lv[q]-mu)*rs*og[j] + ob[j], wp[j], s);
  }
  #pragma unroll
  for (int off = 32; off > 0; off >>= 1) s += __shfl_down(s, off);
  if (lane == 0) out[e] = s + pb[e];
}

extern "C" void kernel_launch(void* const* d_in, const int* in_sizes, int n_in,
                              void* d_out, int out_size, void* d_ws, size_t ws_size,
                              hipStream_t stream) {
  const float* x      = (const float*)d_in[0];
  const float* conv_w = (const float*)d_in[1];
  const float* conv_b = (const float*)d_in[2];
  const float* wi  = (const float*)d_in[3];
  const float* wf  = (const float*)d_in[4];
  const float* wo  = (const float*)d_in[5];
  const float* wz  = (const float*)d_in[6];
  const float* rwi = (const float*)d_in[7];
  const float* rwf = (const float*)d_in[8];
  const float* rwo = (const float*)d_in[9];
  const float* rwz = (const float*)d_in[10];
  const float* bi  = (const float*)d_in[11];
  const float* bf  = (const float*)d_in[12];
  const float* bo  = (const float*)d_in[13];
  const float* bz  = (const float*)d_in[14];
  const float* ln_g  = (const float*)d_in[15];
  const float* ln_b  = (const float*)d_in[16];
  const float* lni_g = (const float*)d_in[17];
  const float* lni_b = (const float*)d_in[18];
  const float* lnf_g = (const float*)d_in[19];
  const float* lnf_b = (const float*)d_in[20];
  const float* lno_g = (const float*)d_in[21];
  const float* lno_b = (const float*)d_in[22];
  const float* lnz_g = (const float*)d_in[23];
  const float* lnz_b = (const float*)d_in[24];
  const float* gn_g  = (const float*)d_in[25];
  const float* gn_b  = (const float*)d_in[26];
  const float* lnc_g = (const float*)d_in[27];
  const float* lnc_b = (const float*)d_in[28];
  const float* lnn_g = (const float*)d_in[29];
  const float* lnn_b = (const float*)d_in[30];
  const float* lnh_g = (const float*)d_in[31];
  const float* lnh_b = (const float*)d_in[32];
  const float* left_w  = (const float*)d_in[33];
  const float* left_b  = (const float*)d_in[34];
  const float* right_w = (const float*)d_in[35];
  const float* right_b = (const float*)d_in[36];
  const float* lnout_g = (const float*)d_in[37];
  const float* lnout_b = (const float*)d_in[38];
  const float* proj_w  = (const float*)d_in[39];
  const float* proj_b  = (const float*)d_in[40];
  const float* nt1 = (const float*)d_in[41];
  const float* ct1 = (const float*)d_in[42];
  const float* ht1 = (const float*)d_in[43];
  const float* mt1 = (const float*)d_in[44];
  float* dout = (float*)d_out;

  char* ws = (char*)d_ws;
  size_t off = 0;
  auto alloc = [&](size_t n) { size_t o = off; off += (n + 255) & ~(size_t)255; return o; };

  const size_t SZ_WT   = 512ull*32768*2;   // 32 MB
  const size_t SZ_XPAD = 4ull*1087*512*2;  // 4.45 MB
  const size_t SZ_PART = 4096ull*512*2;    // 4 MB per split (bf16)
  const size_t SZ_OBUF = 4096ull*512*4;    // 8 MB
  const size_t tail = SZ_OBUF + 2*(512*512*4 + 256) + (256*512*4 + 256) + 6*4096;

  int S;
  bool use256;
  if (SZ_WT + SZ_XPAD + 8*SZ_PART + tail + 65536 <= ws_size) { S = 8; use256 = true; }
  else if (SZ_WT + SZ_XPAD + 4*SZ_PART + tail + 65536 <= ws_size) { S = 4; use256 = false; }
  else { S = 2; use256 = false; }

  const size_t o_wt   = alloc(SZ_WT);
  const size_t o_xpad = alloc(SZ_XPAD);
  const size_t o_part = alloc((size_t)S * SZ_PART);
  const size_t o_obuf = alloc(SZ_OBUF);
  const size_t o_rv   = alloc(4*512*4);
  const size_t o_pct  = alloc(512*512*4);
  const size_t o_pnt  = alloc(512*512*4);
  const size_t o_pht  = alloc(256*512*4);
  const size_t o_r    = alloc(512*4);
  const size_t o_hm   = alloc(512*4);
  const size_t o_lr   = alloc(682*4);

  u16*   wt    = (u16*)(ws + o_wt);
  u16*   xpad  = (u16*)(ws + o_xpad);
  u16*   part  = (u16*)(ws + o_part);
  float* obuf  = (float*)(ws + o_obuf);
  float* rv    = (float*)(ws + o_rv);
  float* pct   = (float*)(ws + o_pct);
  float* pnt   = (float*)(ws + o_pnt);
  float* pht   = (float*)(ws + o_pht);
  float* rbuf  = (float*)(ws + o_r);
  float* hmbuf = (float*)(ws + o_hm);
  float* lrbuf = (float*)(ws + o_lr);

  const int bdgLds = 4*8*512*4 + 2*8*68*4;     // 69888 B -> 2 blocks/CU
  (void)hipFuncSetAttribute((const void*)k_bdg3, hipFuncAttributeMaxDynamicSharedMemorySize, bdgLds);

  k_prep<<<6397, 256, 0, stream>>>(conv_w, wt, rwi, rwf, rwo, rwz, ht1, rv,
                                   x, ln_g, ln_b, xpad);
  if (use256) {
    const int gemmLds = 2 * 65536;             // 128 KiB double buffer
    (void)hipFuncSetAttribute((const void*)k_gemm256, hipFuncAttributeMaxDynamicSharedMemorySize, gemmLds);
    k_gemm256<<<dim3(16, 2, 8), 512, gemmLds, stream>>>(wt, xpad, part, 512 / 8);
  } else {
    k_gemm128<<<dim3(32, 4, S), 512, 0, stream>>>(wt, xpad, part, 512 / S);
  }
  k_bdg3<<<512, 512, bdgLds, stream>>>(part, S, conv_b, xpad,
      wi, wf, wo, wz, bi, bf, bo, bz, rv,
      lni_g, lni_b, lnf_g, lnf_b, lno_g, lno_b, lnz_g, lnz_b,
      lnc_g, lnc_b, lnn_g, lnn_b, mt1, ct1, nt1,
      obuf, pct, pnt);
  k_r<<<512, 256, 0, stream>>>(pct, pnt, rbuf);
  k_ht<<<256, 256, 0, stream>>>(obuf, rbuf, lnh_g, lnh_b, pht);
  k_hm<<<512, 256, 0, stream>>>(pht, hmbuf);
  k_lr2<<<682, 64, 0, stream>>>(hmbuf, gn_g, gn_b,
      left_w, left_b, right_w, right_b, lrbuf);
  k_projln<<<512, 64, 0, stream>>>(lrbuf, lnout_g, lnout_b, proj_w, proj_b, dout);
}

// Round 17
// 234.814 us; speedup vs baseline: 1.1948x; 1.1948x over previous
//
#include <hip/hip_runtime.h>

typedef unsigned short u16;
typedef unsigned int   u32;

using bf16x8 = __attribute__((ext_vector_type(8))) __bf16;
using f32x4  = __attribute__((ext_vector_type(4))) float;

#define EPS 1e-5f

__device__ __forceinline__ u16 f2bf(float f) {
  u32 u = __float_as_uint(f);
  u32 r = (u + 0x7FFFu + ((u >> 16) & 1u)) >> 16;
  return (u16)r;
}
__device__ __forceinline__ float bf2f(u16 h) {
  return __uint_as_float(((u32)h) << 16);
}

__device__ __forceinline__ void gload16(const void* g, void* l) {
  __builtin_amdgcn_global_load_lds((__attribute__((address_space(1))) void*)(void*)g,
                                   (__attribute__((address_space(3))) void*)l,
                                   16, 0, 0);
}

// 2-value block reduction (sum), blockDim in {256,512}; sm >= 2*(blockDim/64)
__device__ __forceinline__ void blockReduce2(float& a, float& b, float* sm) {
  #pragma unroll
  for (int off = 32; off > 0; off >>= 1) {
    a += __shfl_down(a, off);
    b += __shfl_down(b, off);
  }
  const int w = threadIdx.x >> 6, l = threadIdx.x & 63;
  const int nw = blockDim.x >> 6;
  __syncthreads();
  if (l == 0) { sm[2*w] = a; sm[2*w+1] = b; }
  __syncthreads();
  a = sm[0]; b = sm[1];
  for (int i = 1; i < nw; ++i) { a += sm[2*i]; b += sm[2*i+1]; }
}

// 2-value full-wave (64 lane) shuffle reduction
__device__ __forceinline__ void red64_2(float& a, float& b) {
  #pragma unroll
  for (int m = 1; m <= 32; m <<= 1) { a += __shfl_xor(a, m); b += __shfl_xor(b, m); }
}

// ---- K1: fused prep. blocks 0..2047: conv_w f32 [O][I][K] -> wt bf16 [O][K][I];
// block 2048: recurrent vectors; blocks 2049..6396: LN(x) -> xpad (+pad zeroing).
__global__ void k_prep(const float* __restrict__ cw, u16* __restrict__ wt,
                       const float* __restrict__ rwi, const float* __restrict__ rwf,
                       const float* __restrict__ rwo, const float* __restrict__ rwz,
                       const float* __restrict__ ht1, float* __restrict__ rv,
                       const float* __restrict__ x, const float* __restrict__ g,
                       const float* __restrict__ bta, u16* __restrict__ xpad) {
  __shared__ float tile[128][65];
  const int bid = blockIdx.x;
  const int tid = threadIdx.x;
  if (bid < 2048) {
    const int o  = bid >> 2;
    const int i0 = (bid & 3) << 7;
    const size_t inBase = ((size_t)(o*512 + i0)) << 6;
    for (int idx = tid; idx < 128*64; idx += 256) {
      const int ii = idx >> 6, k = idx & 63;
      tile[ii][k] = cw[inBase + ((size_t)ii << 6) + k];
    }
    __syncthreads();
    const size_t outBase = ((size_t)o << 15) + i0;
    for (int idx = tid; idx < 128*64; idx += 256) {
      const int k = idx >> 7, ii = idx & 127;
      wt[outBase + ((size_t)k << 9) + ii] = f2bf(tile[ii][k]);
    }
    return;
  }
  if (bid == 2048) {
    const float* w[4] = {rwi, rwf, rwo, rwz};
    for (int gg = 0; gg < 4; ++gg)
      for (int e = tid; e < 512; e += 256) {
        const float* wr = w[gg] + e*64;
        const float* hv = ht1 + (e >> 6)*64;
        float s = 0.f;
        for (int i = 0; i < 64; ++i) s = fmaf(wr[i], hv[i], s);
        rv[gg*512 + e] = s;
      }
    return;
  }
  const int row = bid - 2049;   // 0..4347
  if (row >= 4096) {
    const int idx = row - 4096;           // 0..251
    const int b = idx / 63, rr = idx % 63;
    const size_t base = ((size_t)(b*1087 + rr)) << 9;
    xpad[base + tid] = 0;
    xpad[base + tid + 256] = 0;
    return;
  }
  const int e0 = tid, e1 = tid + 256;
  const size_t ib = (size_t)row << 9;
  const float v0 = x[ib + e0], v1 = x[ib + e1];
  float a = v0 + v1, b2 = v0*v0 + v1*v1;
  blockReduce2(a, b2, (float*)tile);
  const float mu = a * (1.f/512.f);
  const float var = b2 * (1.f/512.f) - mu*mu;
  const float rs = rsqrtf(var + EPS);
  const int bb = row >> 10, t = row & 1023;
  const size_t ob = ((size_t)(bb*1087 + 63 + t)) << 9;
  xpad[ob + e0] = f2bf((v0 - mu) * rs * g[e0] + bta[e0]);
  xpad[ob + e1] = f2bf((v1 - mu) * rs * g[e1] + bta[e1]);
}

// ---- K3: conv-as-GEMM, 256x256 tile, BK=64, split-K=8, bf16 partials.
// R12-proven barrier-minimal tile schedule (unchanged).
__global__ __launch_bounds__(512) void k_gemm256(
    const u16* __restrict__ wt, const u16* __restrict__ xpad,
    u16* __restrict__ part, int kSteps)
{
  extern __shared__ __align__(16) char smem[];   // 2 x 65536
  const int tid  = threadIdx.x;
  const int lane = tid & 63;
  const int wid  = tid >> 6;
  const int wm = wid >> 2, wn = wid & 3;          // 2M x 4N waves, 128x64 out each
  const int mb = blockIdx.x, nb = blockIdx.y, sp = blockIdx.z;

  const int wmBase = wm * 128;
  const int wnBase = wn * 64;
  const int l15  = lane & 15;
  const int kb16 = (lane >> 4) << 4;

  const int srow = tid >> 3;
  const int scb  = (tid & 7) << 4;
  const int csrcE = (scb ^ ((srow & 7) << 4)) >> 1;   // pre-swizzled source col

  const u16* aB0;
  {
    const int m0 = mb*256 + srow;          // 256-chunks never cross a batch boundary
    const int b = m0 >> 10, t = m0 & 1023;
    aB0 = xpad + (((size_t)(b*1087 + t)) << 9) + csrcE;   // NO +63 (R8 bug)
  }
  const u16* bB0 = wt + (((size_t)(nb*256 + srow)) << 15) + csrcE;
  const size_t dst16 = (size_t)tid * 16;

  f32x4 acc[8][4];
  const f32x4 zero4 = {0.f, 0.f, 0.f, 0.f};
  #pragma unroll
  for (int i = 0; i < 8; ++i)
    #pragma unroll
    for (int j = 0; j < 4; ++j) acc[i][j] = zero4;

  const int kBase = sp * kSteps;

  auto STAGE = [&](int ktg, char* buf) {
    const size_t aOff = ((size_t)(ktg >> 3) << 9) + ((size_t)(ktg & 7) << 6);
    const size_t bOff = (size_t)ktg << 6;
    gload16(aB0 + aOff,                  buf + dst16);
    gload16(aB0 + (64ull << 9) + aOff,   buf +  8192 + dst16);
    gload16(aB0 + (128ull << 9) + aOff,  buf + 16384 + dst16);
    gload16(aB0 + (192ull << 9) + aOff,  buf + 24576 + dst16);
    gload16(bB0 + bOff,                   buf + 32768 + dst16);
    gload16(bB0 + (64ull << 15) + bOff,   buf + 40960 + dst16);
    gload16(bB0 + (128ull << 15) + bOff,  buf + 49152 + dst16);
    gload16(bB0 + (192ull << 15) + bOff,  buf + 57344 + dst16);
  };

  STAGE(kBase, smem);
  __syncthreads();

  for (int kt = 0; kt < kSteps; ++kt) {
    const char* curA = smem + (size_t)(kt & 1) * 65536;
    const char* curB = curA + 32768;
    char* nxt = smem + (size_t)((kt & 1) ^ 1) * 65536;
    if (kt + 1 < kSteps) STAGE(kBase + kt + 1, nxt);

    bf16x8 bv[4][2];
    #pragma unroll
    for (int nr = 0; nr < 4; ++nr) {
      const int r = wnBase + nr*16 + l15;
      const int sw = (r & 7) << 4;
      bv[nr][0] = *(const bf16x8*)(curB + r*128 + ((kb16     ) ^ sw));
      bv[nr][1] = *(const bf16x8*)(curB + r*128 + ((kb16 + 64) ^ sw));
    }
    #pragma unroll
    for (int q = 0; q < 4; ++q) {
      bf16x8 af0, af0b, af1, af1b;
      { const int r = wmBase + q*32 + l15; const int sw = (r & 7) << 4;
        af0  = *(const bf16x8*)(curA + r*128 + ((kb16     ) ^ sw));
        af0b = *(const bf16x8*)(curA + r*128 + ((kb16 + 64) ^ sw)); }
      { const int r = wmBase + q*32 + 16 + l15; const int sw = (r & 7) << 4;
        af1  = *(const bf16x8*)(curA + r*128 + ((kb16     ) ^ sw));
        af1b = *(const bf16x8*)(curA + r*128 + ((kb16 + 64) ^ sw)); }
      #pragma unroll
      for (int nr = 0; nr < 4; ++nr) {
        acc[2*q][nr]   = __builtin_amdgcn_mfma_f32_16x16x32_bf16(af0,  bv[nr][0], acc[2*q][nr],   0, 0, 0);
        acc[2*q][nr]   = __builtin_amdgcn_mfma_f32_16x16x32_bf16(af0b, bv[nr][1], acc[2*q][nr],   0, 0, 0);
        acc[2*q+1][nr] = __builtin_amdgcn_mfma_f32_16x16x32_bf16(af1,  bv[nr][0], acc[2*q+1][nr], 0, 0, 0);
        acc[2*q+1][nr] = __builtin_amdgcn_mfma_f32_16x16x32_bf16(af1b, bv[nr][1], acc[2*q+1][nr], 0, 0, 0);
      }
    }
    __syncthreads();
  }

  u16* outp = part + (size_t)sp * 4096 * 512;
  #pragma unroll
  for (int mr = 0; mr < 8; ++mr)
    #pragma unroll
    for (int nr = 0; nr < 4; ++nr)
      #pragma unroll
      for (int r4 = 0; r4 < 4; ++r4) {
        const int row = mb*256 + wmBase + mr*16 + ((lane >> 4) << 2) + r4;
        const int col = nb*256 + wnBase + nr*16 + l15;
        outp[((size_t)row << 9) + col] = f2bf(acc[mr][nr][r4]);
      }
}

// ---- K3 (fallback): R10-proven 128x128 tile, static 32KB LDS (bf16 partials).
__global__ __launch_bounds__(512) void k_gemm128(
    const u16* __restrict__ wt, const u16* __restrict__ xpad,
    u16* __restrict__ part, int kSteps)
{
  __shared__ __align__(16) u16 lsA[128*64];
  __shared__ __align__(16) u16 lsB[128*64];
  const int tid  = threadIdx.x;
  const int lane = tid & 63;
  const int wid  = tid >> 6;
  const int wm = wid >> 2, wn = wid & 3;
  const int mb = blockIdx.x, nb = blockIdx.y, sp = blockIdx.z;

  const int srow = tid >> 3;
  const int scb  = (tid & 7) << 4;
  const int csrcE = (scb ^ ((srow & 7) << 4)) >> 1;

  const int m0 = mb*128 + srow, m1 = m0 + 64;
  const int b0 = m0 >> 10, t0 = m0 & 1023;
  const int b1 = m1 >> 10, t1 = m1 & 1023;
  const u16* aB0 = xpad + (((size_t)(b0*1087 + t0)) << 9) + csrcE;
  const u16* aB1 = xpad + (((size_t)(b1*1087 + t1)) << 9) + csrcE;
  const u16* bB0 = wt + (((size_t)(nb*128 + srow)) << 15) + csrcE;
  const u16* bB1 = wt + (((size_t)(nb*128 + srow + 64)) << 15) + csrcE;
  u16* dA0 = &lsA[tid*8]; u16* dA1 = &lsA[4096 + tid*8];
  u16* dB0 = &lsB[tid*8]; u16* dB1 = &lsB[4096 + tid*8];

  const f32x4 zero4 = {0.f, 0.f, 0.f, 0.f};
  f32x4 acc[4][2];
  #pragma unroll
  for (int i = 0; i < 4; ++i)
    #pragma unroll
    for (int j = 0; j < 2; ++j) acc[i][j] = zero4;

  const int kBase = sp * kSteps;
  for (int kt = 0; kt < kSteps; ++kt) {
    const int ktg = kBase + kt;
    const int k  = ktg >> 3;
    const int i0 = (ktg & 7) << 6;
    const int aStep = (k << 9) + i0;
    gload16(aB0 + aStep, dA0);
    gload16(aB1 + aStep, dA1);
    gload16(bB0 + ((size_t)ktg << 6), dB0);
    gload16(bB1 + ((size_t)ktg << 6), dB1);
    __syncthreads();
    #pragma unroll
    for (int ks = 0; ks < 2; ++ks) {
      bf16x8 af[4], bv[2];
      #pragma unroll
      for (int mr = 0; mr < 4; ++mr) {
        const int r  = wm*64 + mr*16 + (lane & 15);
        const int cb = (ks << 6) + ((lane >> 4) << 4);
        af[mr] = *(const bf16x8*)((const char*)lsA + (r*128 + (cb ^ ((r & 7) << 4))));
      }
      #pragma unroll
      for (int nr = 0; nr < 2; ++nr) {
        const int r  = wn*32 + nr*16 + (lane & 15);
        const int cb = (ks << 6) + ((lane >> 4) << 4);
        bv[nr] = *(const bf16x8*)((const char*)lsB + (r*128 + (cb ^ ((r & 7) << 4))));
      }
      #pragma unroll
      for (int mr = 0; mr < 4; ++mr)
        #pragma unroll
        for (int nr = 0; nr < 2; ++nr)
          acc[mr][nr] = __builtin_amdgcn_mfma_f32_16x16x32_bf16(af[mr], bv[nr], acc[mr][nr], 0, 0, 0);
    }
    __syncthreads();
  }

  u16* outp = part + (size_t)sp * 4096 * 512;
  #pragma unroll
  for (int mr = 0; mr < 4; ++mr)
    #pragma unroll
    for (int nr = 0; nr < 2; ++nr)
      #pragma unroll
      for (int r4 = 0; r4 < 4; ++r4) {
        const int row = mb*128 + wm*64 + mr*16 + ((lane >> 4) << 2) + r4;
        const int col = nb*128 + wn*32 + nr*16 + (lane & 15);
        outp[((size_t)row << 9) + col] = f2bf(acc[mr][nr][r4]);
      }
}

// ---- K5: fused fp32 block-diag gates + LNs + gating + ct/nt partials.
// R14 16-row mapping; x-staging DOUBLE-BUFFERED -> 1 barrier/d, latency hidden.
__global__ __launch_bounds__(512, 2) void k_bdg3(
    const u16* __restrict__ part, int S,
    const float* __restrict__ cb, const u16* __restrict__ xpad,
    const float* __restrict__ wi, const float* __restrict__ wf,
    const float* __restrict__ wo, const float* __restrict__ wz,
    const float* __restrict__ bi, const float* __restrict__ bf_,
    const float* __restrict__ bo, const float* __restrict__ bz,
    const float* __restrict__ rv,
    const float* __restrict__ lnig, const float* __restrict__ lnib,
    const float* __restrict__ lnfg, const float* __restrict__ lnfb,
    const float* __restrict__ lnog, const float* __restrict__ lnob,
    const float* __restrict__ lnzg, const float* __restrict__ lnzb,
    const float* __restrict__ lncg, const float* __restrict__ lncb,
    const float* __restrict__ lnng, const float* __restrict__ lnnb,
    const float* __restrict__ mt1, const float* __restrict__ ct1,
    const float* __restrict__ nt1,
    float* __restrict__ obuf, float* __restrict__ pct, float* __restrict__ pnt)
{
  extern __shared__ char smem2[];
  float* pre4 = (float*)smem2;                 // [4][16][512] f32 = 131072 B
  float* xbuf = (float*)(smem2 + 131072);      // [2][2][16][68] dbuf (17408 B)
  float* pctW = pre4;                          // [8][512] phase-2 reuse
  float* pntW = pre4 + 8*512;

  const int tid  = threadIdx.x;
  const int lane = tid & 63;
  const int w    = tid >> 6;
  const int g    = w >> 1;
  const int rh   = w & 1;
  const int rowBase = blockIdx.x * 16;
  const size_t N = 4096ull*512;
  const float* wptr[4] = {wi, wf, wo, wz};
  const float* bptr[4] = {bi, bf_, bo, bz};
  const float* wg = wptr[g];
  const float* bg = bptr[g];

  const int sr    = tid >> 5;          // staging row 0..15
  const int scol2 = (tid & 31) << 1;   // staging col pair

  auto STAGEX = [&](int d, int b) {
    float* xsc = xbuf + (size_t)b * 2*16*68;
    float* xsl = xsc + 16*68;
    const int row = rowBase + sr, col = d*64 + scol2;
    float v0 = cb[col], v1 = cb[col+1];
    for (int s = 0; s < S; ++s) {
      const u32 p = *(const u32*)&part[(size_t)s*N + (size_t)row*512 + col];
      v0 += bf2f((u16)p);
      v1 += bf2f((u16)(p >> 16));
    }
    xsc[sr*68 + scol2]     = v0 / (1.f + expf(-v0));
    xsc[sr*68 + scol2 + 1] = v1 / (1.f + expf(-v1));
    const int bq = row >> 10, tt = row & 1023;
    const u32 xp = *(const u32*)&xpad[(((size_t)(bq*1087 + 63 + tt)) << 9) + col];
    xsl[sr*68 + scol2]     = bf2f((u16)xp);
    xsl[sr*68 + scol2 + 1] = bf2f((u16)(xp >> 16));
  };

  STAGEX(0, 0);
  __syncthreads();

  for (int d = 0; d < 8; ++d) {
    if (d + 1 < 8) STAGEX(d + 1, (d + 1) & 1);   // writes other buffer

    float4 wreg[16];
    {
      const float* wb = wg + (size_t)d*4096 + lane*64;
      #pragma unroll
      for (int j = 0; j < 16; ++j) wreg[j] = *(const float4*)(wb + 4*j);
    }

    const float* xsc = xbuf + (size_t)(d & 1) * 2*16*68;
    const float* X = (g < 2) ? xsc : (xsc + 16*68);
    float acc[8];
    #pragma unroll
    for (int r8 = 0; r8 < 8; ++r8) acc[r8] = 0.f;
    #pragma unroll
    for (int i4 = 0; i4 < 16; ++i4) {
      const float4 wv = wreg[i4];
      #pragma unroll
      for (int r8 = 0; r8 < 8; ++r8) {
        const float4 xv = *(const float4*)(X + (rh*8 + r8)*68 + (i4 << 2));
        acc[r8] = fmaf(xv.w, wv.w, fmaf(xv.z, wv.z, fmaf(xv.y, wv.y, fmaf(xv.x, wv.x, acc[r8]))));
      }
    }
    const int e = d*64 + lane;
    const float bias = bg[e] + rv[g*512 + e];
    #pragma unroll
    for (int r8 = 0; r8 < 8; ++r8)
      pre4[(g*16 + rh*8 + r8)*512 + e] = acc[r8] + bias;

    __syncthreads();   // next-iter buffer staged; this-iter reads complete
  }

  // phase 2 (R14-exact)
  float pcA[8], pnA[8];
  #pragma unroll
  for (int j = 0; j < 8; ++j) { pcA[j] = 0.f; pnA[j] = 0.f; }
  for (int rr = 0; rr < 2; ++rr) {
    const int prow = 2*w + rr;
    const int grow = rowBase + prow;
    float gi[8], gf[8], go_[8], gz[8];
    #pragma unroll
    for (int j = 0; j < 8; ++j) {
      const int c = lane + 64*j;
      gi[j]  = pre4[(0*16 + prow)*512 + c];
      gf[j]  = pre4[(1*16 + prow)*512 + c];
      go_[j] = pre4[(2*16 + prow)*512 + c];
      gz[j]  = pre4[(3*16 + prow)*512 + c];
    }
    float si=0,si2=0,sf=0,sf2=0,so=0,so2=0,sz=0,sz2=0;
    #pragma unroll
    for (int j = 0; j < 8; ++j) {
      si += gi[j];  si2 += gi[j]*gi[j];
      sf += gf[j];  sf2 += gf[j]*gf[j];
      so += go_[j]; so2 += go_[j]*go_[j];
      sz += gz[j];  sz2 += gz[j]*gz[j];
    }
    red64_2(si, si2); red64_2(sf, sf2); red64_2(so, so2); red64_2(sz, sz2);
    const float mui = si*(1.f/512.f), rsi = rsqrtf(si2*(1.f/512.f) - mui*mui + EPS);
    const float muf = sf*(1.f/512.f), rsf = rsqrtf(sf2*(1.f/512.f) - muf*muf + EPS);
    const float muo = so*(1.f/512.f), rso = rsqrtf(so2*(1.f/512.f) - muo*muo + EPS);
    const float muz = sz*(1.f/512.f), rsz = rsqrtf(sz2*(1.f/512.f) - muz*muz + EPS);

    float ctv[8], ntv[8];
    float cS=0,cS2=0,nS=0,nS2=0;
    #pragma unroll
    for (int j = 0; j < 8; ++j) {
      const int c = lane + 64*j;
      const float li = (gi[j]-mui)*rsi*lnig[c] + lnib[c];
      const float lf = (gf[j]-muf)*rsf*lnfg[c] + lnfb[c];
      const float ov = 1.f/(1.f+expf(-((go_[j]-muo)*rso*lnog[c] + lnob[c])));
      const float zv = tanhf((gz[j]-muz)*rsz*lnzg[c] + lnzb[c]);
      obuf[(size_t)grow*512 + c] = ov;
      const float lfm = lf + mt1[c];
      const float mm = fmaxf(lfm, li);
      const float iv = expf(li - mm), fv = expf(lfm - mm);
      ctv[j] = fv*ct1[c] + iv*zv;
      ntv[j] = fv*nt1[c] + iv;
      cS += ctv[j]; cS2 += ctv[j]*ctv[j];
      nS += ntv[j]; nS2 += ntv[j]*ntv[j];
    }
    red64_2(cS, cS2); red64_2(nS, nS2);
    const float muc = cS*(1.f/512.f), rsc = rsqrtf(cS2*(1.f/512.f) - muc*muc + EPS);
    const float mun = nS*(1.f/512.f), rsn = rsqrtf(nS2*(1.f/512.f) - mun*mun + EPS);
    #pragma unroll
    for (int j = 0; j < 8; ++j) {
      const int c = lane + 64*j;
      pcA[j] += (ctv[j]-muc)*rsc*lncg[c] + lncb[c];
      pnA[j] += (ntv[j]-mun)*rsn*lnng[c] + lnnb[c];
    }
  }
  __syncthreads();
  #pragma unroll
  for (int j = 0; j < 8; ++j) {
    const int c = lane + 64*j;
    pctW[w*512 + c] = pcA[j];
    pntW[w*512 + c] = pnA[j];
  }
  __syncthreads();
  {
    const int e = tid;
    float cs = 0.f, ns = 0.f;
    #pragma unroll
    for (int ww = 0; ww < 8; ++ww) { cs += pctW[ww*512 + e]; ns += pntW[ww*512 + e]; }
    pct[(size_t)blockIdx.x*512 + e] = cs;
    pnt[(size_t)blockIdx.x*512 + e] = ns;
  }
}

// ---- K5b: r[e] = sum_b(pct)/sum_b(pnt) over 256 partials; 512 blocks x 256 thr
__global__ void k_r(const float* __restrict__ pct, const float* __restrict__ pnt,
                    float* __restrict__ rout) {
  __shared__ float sm[8];
  const int e = blockIdx.x, tid = threadIdx.x;
  float cs = pct[(size_t)tid*512 + e];
  float ns = pnt[(size_t)tid*512 + e];
  blockReduce2(cs, ns, sm);
  if (tid == 0) rout[e] = cs / ns;
}

// ---- K6: ht-row LN accumulation, wave-per-row (256 blocks x 16 rows)
__global__ __launch_bounds__(256) void k_ht(
    const float* __restrict__ obuf, const float* __restrict__ r,
    const float* __restrict__ lnhg, const float* __restrict__ lnhb,
    float* __restrict__ phtPart)
{
  __shared__ float rsh[512];
  __shared__ float phtW[4][512];
  const int tid = threadIdx.x, lane = tid & 63, w = tid >> 6;
  rsh[tid] = r[tid]; rsh[tid + 256] = r[tid + 256];
  __syncthreads();
  float accH[8] = {0,0,0,0,0,0,0,0};
  const int rowBase = blockIdx.x * 16;
  for (int rr = 0; rr < 4; ++rr) {
    const int row = rowBase + w*4 + rr;
    float v[8], s = 0.f, s2 = 0.f;
    #pragma unroll
    for (int j = 0; j < 8; ++j) {
      const int c = lane + 64*j;
      v[j] = obuf[(size_t)row*512 + c] * rsh[c];
      s += v[j]; s2 += v[j]*v[j];
    }
    #pragma unroll
    for (int m = 1; m <= 32; m <<= 1) { s += __shfl_xor(s, m); s2 += __shfl_xor(s2, m); }
    const float mu = s*(1.f/512.f), rs = rsqrtf(s2*(1.f/512.f) - mu*mu + EPS);
    #pragma unroll
    for (int j = 0; j < 8; ++j) {
      const int c = lane + 64*j;
      accH[j] += (v[j]-mu)*rs*lnhg[c] + lnhb[c];
    }
  }
  #pragma unroll
  for (int j = 0; j < 8; ++j) phtW[w][lane + 64*j] = accH[j];
  __syncthreads();
  const int e0 = tid, e1 = tid + 256;
  float h0 = 0.f, h1 = 0.f;
  #pragma unroll
  for (int ww = 0; ww < 4; ++ww) { h0 += phtW[ww][e0]; h1 += phtW[ww][e1]; }
  phtPart[(size_t)blockIdx.x*512 + e0] = h0;
  phtPart[(size_t)blockIdx.x*512 + e1] = h1;
}

// ---- K6b: htm[e] = (sum_b pht[b][e]) / 4096; 512 blocks x 256 thr
__global__ void k_hm(const float* __restrict__ pht, float* __restrict__ hm) {
  __shared__ float sm[8];
  const int e = blockIdx.x, tid = threadIdx.x;
  float v = pht[(size_t)tid*512 + e];
  float d = 0.f;
  blockReduce2(v, d, sm);
  if (tid == 0) hm[e] = v * (1.f/4096.f);
}

// ---- K7: fused gn-LN + left/right GEMV + gelu; 682 blocks x 64.
__global__ void k_lr2(const float* __restrict__ hm,
                      const float* __restrict__ gng, const float* __restrict__ gnb,
                      const float* __restrict__ lw, const float* __restrict__ lb,
                      const float* __restrict__ rw, const float* __restrict__ rb_,
                      float* __restrict__ lr) {
  const int j = blockIdx.x, lane = threadIdx.x;
  float h[8];
  float a = 0.f, b2 = 0.f;
  #pragma unroll
  for (int q = 0; q < 8; ++q) {
    h[q] = hm[lane + 64*q];
    a += h[q]; b2 += h[q]*h[q];
  }
  red64_2(a, b2);
  const float mu = a*(1.f/512.f), rs = rsqrtf(b2*(1.f/512.f) - mu*mu + EPS);
  const float* lwp = lw + (size_t)j*512;
  const float* rwp = rw + (size_t)j*512;
  float dl = 0.f, dr = 0.f;
  #pragma unroll
  for (int q = 0; q < 8; ++q) {
    const int e = lane + 64*q;
    const float sv = (h[q]-mu)*rs*gng[e] + gnb[e];
    dl = fmaf(lwp[e], sv, dl);
    dr = fmaf(rwp[e], sv, dr);
  }
  #pragma unroll
  for (int off = 32; off > 0; off >>= 1) { dl += __shfl_down(dl, off); dr += __shfl_down(dr, off); }
  if (lane == 0) {
    const float L = dl + lb[j];
    const float R = dr + rb_[j];
    const float gelu = 0.5f*R*(1.f + erff(R*0.70710678118654752440f));
    lr[j] = L * gelu;
  }
}

// ---- K8: fused LN(lr) + proj: 512 blocks x 64 lanes
__global__ void k_projln(const float* __restrict__ lr,
                         const float* __restrict__ og, const float* __restrict__ ob,
                         const float* __restrict__ pw, const float* __restrict__ pb,
                         float* __restrict__ out) {
  const int e = blockIdx.x, lane = threadIdx.x;
  float lv[11];
  float a = 0.f, b2 = 0.f;
  #pragma unroll
  for (int q = 0; q < 11; ++q) {
    const int j = lane + 64*q;
    const float v = (j < 682) ? lr[j] : 0.f;
    lv[q] = v;
    a += v; b2 += v*v;
  }
  red64_2(a, b2);
  const float mu = a*(1.f/682.f), rs = rsqrtf(b2*(1.f/682.f) - mu*mu + EPS);
  const float* wp = pw + (size_t)e*682;
  float s = 0.f;
  #pragma unroll
  for (int q = 0; q < 11; ++q) {
    const int j = lane + 64*q;
    if (j < 682) s = fmaf((lv[q]-mu)*rs*og[j] + ob[j], wp[j], s);
  }
  #pragma unroll
  for (int off = 32; off > 0; off >>= 1) s += __shfl_down(s, off);
  if (lane == 0) out[e] = s + pb[e];
}

extern "C" void kernel_launch(void* const* d_in, const int* in_sizes, int n_in,
                              void* d_out, int out_size, void* d_ws, size_t ws_size,
                              hipStream_t stream) {
  const float* x      = (const float*)d_in[0];
  const float* conv_w = (const float*)d_in[1];
  const float* conv_b = (const float*)d_in[2];
  const float* wi  = (const float*)d_in[3];
  const float* wf  = (const float*)d_in[4];
  const float* wo  = (const float*)d_in[5];
  const float* wz  = (const float*)d_in[6];
  const float* rwi = (const float*)d_in[7];
  const float* rwf = (const float*)d_in[8];
  const float* rwo = (const float*)d_in[9];
  const float* rwz = (const float*)d_in[10];
  const float* bi  = (const float*)d_in[11];
  const float* bf  = (const float*)d_in[12];
  const float* bo  = (const float*)d_in[13];
  const float* bz  = (const float*)d_in[14];
  const float* ln_g  = (const float*)d_in[15];
  const float* ln_b  = (const float*)d_in[16];
  const float* lni_g = (const float*)d_in[17];
  const float* lni_b = (const float*)d_in[18];
  const float* lnf_g = (const float*)d_in[19];
  const float* lnf_b = (const float*)d_in[20];
  const float* lno_g = (const float*)d_in[21];
  const float* lno_b = (const float*)d_in[22];
  const float* lnz_g = (const float*)d_in[23];
  const float* lnz_b = (const float*)d_in[24];
  const float* gn_g  = (const float*)d_in[25];
  const float* gn_b  = (const float*)d_in[26];
  const float* lnc_g = (const float*)d_in[27];
  const float* lnc_b = (const float*)d_in[28];
  const float* lnn_g = (const float*)d_in[29];
  const float* lnn_b = (const float*)d_in[30];
  const float* lnh_g = (const float*)d_in[31];
  const float* lnh_b = (const float*)d_in[32];
  const float* left_w  = (const float*)d_in[33];
  const float* left_b  = (const float*)d_in[34];
  const float* right_w = (const float*)d_in[35];
  const float* right_b = (const float*)d_in[36];
  const float* lnout_g = (const float*)d_in[37];
  const float* lnout_b = (const float*)d_in[38];
  const float* proj_w  = (const float*)d_in[39];
  const float* proj_b  = (const float*)d_in[40];
  const float* nt1 = (const float*)d_in[41];
  const float* ct1 = (const float*)d_in[42];
  const float* ht1 = (const float*)d_in[43];
  const float* mt1 = (const float*)d_in[44];
  float* dout = (float*)d_out;

  char* ws = (char*)d_ws;
  size_t off = 0;
  auto alloc = [&](size_t n) { size_t o = off; off += (n + 255) & ~(size_t)255; return o; };

  const size_t SZ_WT   = 512ull*32768*2;   // 32 MB
  const size_t SZ_XPAD = 4ull*1087*512*2;  // 4.45 MB
  const size_t SZ_PART = 4096ull*512*2;    // 4 MB per split (bf16)
  const size_t SZ_OBUF = 4096ull*512*4;    // 8 MB
  const size_t tail = SZ_OBUF + 3*(256*512*4 + 256) + 6*4096;

  int S;
  bool use256;
  if (SZ_WT + SZ_XPAD + 8*SZ_PART + tail + 65536 <= ws_size) { S = 8; use256 = true; }
  else if (SZ_WT + SZ_XPAD + 4*SZ_PART + tail + 65536 <= ws_size) { S = 4; use256 = false; }
  else { S = 2; use256 = false; }

  const size_t o_wt   = alloc(SZ_WT);
  const size_t o_xpad = alloc(SZ_XPAD);
  const size_t o_part = alloc((size_t)S * SZ_PART);
  const size_t o_obuf = alloc(SZ_OBUF);
  const size_t o_rv   = alloc(4*512*4);
  const size_t o_pct  = alloc(256*512*4);
  const size_t o_pnt  = alloc(256*512*4);
  const size_t o_pht  = alloc(256*512*4);
  const size_t o_r    = alloc(512*4);
  const size_t o_hm   = alloc(512*4);
  const size_t o_lr   = alloc(682*4);

  u16*   wt    = (u16*)(ws + o_wt);
  u16*   xpad  = (u16*)(ws + o_xpad);
  u16*   part  = (u16*)(ws + o_part);
  float* obuf  = (float*)(ws + o_obuf);
  float* rv    = (float*)(ws + o_rv);
  float* pct   = (float*)(ws + o_pct);
  float* pnt   = (float*)(ws + o_pnt);
  float* pht   = (float*)(ws + o_pht);
  float* rbuf  = (float*)(ws + o_r);
  float* hmbuf = (float*)(ws + o_hm);
  float* lrbuf = (float*)(ws + o_lr);

  const int bdgLds = 4*16*512*4 + 2*2*16*68*4;   // 131072 + 17408 = 148480 B
  (void)hipFuncSetAttribute((const void*)k_bdg3, hipFuncAttributeMaxDynamicSharedMemorySize, bdgLds);

  k_prep<<<6397, 256, 0, stream>>>(conv_w, wt, rwi, rwf, rwo, rwz, ht1, rv,
                                   x, ln_g, ln_b, xpad);
  if (use256) {
    const int gemmLds = 2 * 65536;             // 128 KiB double buffer
    (void)hipFuncSetAttribute((const void*)k_gemm256, hipFuncAttributeMaxDynamicSharedMemorySize, gemmLds);
    k_gemm256<<<dim3(16, 2, 8), 512, gemmLds, stream>>>(wt, xpad, part, 512 / 8);
  } else {
    k_gemm128<<<dim3(32, 4, S), 512, 0, stream>>>(wt, xpad, part, 512 / S);
  }
  k_bdg3<<<256, 512, bdgLds, stream>>>(part, S, conv_b, xpad,
      wi, wf, wo, wz, bi, bf, bo, bz, rv,
      lni_g, lni_b, lnf_g, lnf_b, lno_g, lno_b, lnz_g, lnz_b,
      lnc_g, lnc_b, lnn_g, lnn_b, mt1, ct1, nt1,
      obuf, pct, pnt);
  k_r<<<512, 256, 0, stream>>>(pct, pnt, rbuf);
  k_ht<<<256, 256, 0, stream>>>(obuf, rbuf, lnh_g, lnh_b, pht);
  k_hm<<<512, 256, 0, stream>>>(pht, hmbuf);
  k_lr2<<<682, 64, 0, stream>>>(hmbuf, gn_g, gn_b,
      left_w, left_b, right_w, right_b, lrbuf);
  k_projln<<<512, 64, 0, stream>>>(lrbuf, lnout_g, lnout_b, proj_w, proj_b, dout);
}

// Round 18
// 214.607 us; speedup vs baseline: 1.3073x; 1.0942x over previous
//
#include <hip/hip_runtime.h>

typedef unsigned short u16;
typedef unsigned int   u32;

using bf16x8 = __attribute__((ext_vector_type(8))) __bf16;
using f32x4  = __attribute__((ext_vector_type(4))) float;

#define EPS 1e-5f

__device__ __forceinline__ u16 f2bf(float f) {
  u32 u = __float_as_uint(f);
  u32 r = (u + 0x7FFFu + ((u >> 16) & 1u)) >> 16;
  return (u16)r;
}
__device__ __forceinline__ float bf2f(u16 h) {
  return __uint_as_float(((u32)h) << 16);
}

__device__ __forceinline__ void gload16(const void* g, void* l) {
  __builtin_amdgcn_global_load_lds((__attribute__((address_space(1))) void*)(void*)g,
                                   (__attribute__((address_space(3))) void*)l,
                                   16, 0, 0);
}

// 2-value block reduction (sum), blockDim in {256,512}; sm >= 2*(blockDim/64)
__device__ __forceinline__ void blockReduce2(float& a, float& b, float* sm) {
  #pragma unroll
  for (int off = 32; off > 0; off >>= 1) {
    a += __shfl_down(a, off);
    b += __shfl_down(b, off);
  }
  const int w = threadIdx.x >> 6, l = threadIdx.x & 63;
  const int nw = blockDim.x >> 6;
  __syncthreads();
  if (l == 0) { sm[2*w] = a; sm[2*w+1] = b; }
  __syncthreads();
  a = sm[0]; b = sm[1];
  for (int i = 1; i < nw; ++i) { a += sm[2*i]; b += sm[2*i+1]; }
}

// 2-value full-wave (64 lane) shuffle reduction
__device__ __forceinline__ void red64_2(float& a, float& b) {
  #pragma unroll
  for (int m = 1; m <= 32; m <<= 1) { a += __shfl_xor(a, m); b += __shfl_xor(b, m); }
}

// ---- K1: fused prep. blocks 0..2047: conv_w f32 [O][I][K] -> wt bf16 [O][K][I];
// block 2048: rvec; 2049..6396: LN(x)->xpad (+pad); 6397..6428: gate-weight
// transpose to wt4[((g*8+d)*16+i4)*256 + o*4 + c] (coalesced reads in k_bdg3).
__global__ void k_prep(const float* __restrict__ cw, u16* __restrict__ wt,
                       const float* __restrict__ rwi, const float* __restrict__ rwf,
                       const float* __restrict__ rwo, const float* __restrict__ rwz,
                       const float* __restrict__ ht1, float* __restrict__ rv,
                       const float* __restrict__ x, const float* __restrict__ g,
                       const float* __restrict__ bta, u16* __restrict__ xpad,
                       const float* __restrict__ wi, const float* __restrict__ wf,
                       const float* __restrict__ wo, const float* __restrict__ wz,
                       float* __restrict__ wt4) {
  __shared__ float tile[128][65];
  const int bid = blockIdx.x;
  const int tid = threadIdx.x;
  if (bid < 2048) {
    const int o  = bid >> 2;
    const int i0 = (bid & 3) << 7;
    const size_t inBase = ((size_t)(o*512 + i0)) << 6;
    for (int idx = tid; idx < 128*64; idx += 256) {
      const int ii = idx >> 6, k = idx & 63;
      tile[ii][k] = cw[inBase + ((size_t)ii << 6) + k];
    }
    __syncthreads();
    const size_t outBase = ((size_t)o << 15) + i0;
    for (int idx = tid; idx < 128*64; idx += 256) {
      const int k = idx >> 7, ii = idx & 127;
      wt[outBase + ((size_t)k << 9) + ii] = f2bf(tile[ii][k]);
    }
    return;
  }
  if (bid == 2048) {
    const float* w[4] = {rwi, rwf, rwo, rwz};
    for (int gg = 0; gg < 4; ++gg)
      for (int e = tid; e < 512; e += 256) {
        const float* wr = w[gg] + e*64;
        const float* hv = ht1 + (e >> 6)*64;
        float s = 0.f;
        for (int i = 0; i < 64; ++i) s = fmaf(wr[i], hv[i], s);
        rv[gg*512 + e] = s;
      }
    return;
  }
  if (bid >= 6397) {
    const int q = bid - 6397;          // 0..31
    const int gg = q >> 3, d = q & 7;
    const float* wptr[4] = {wi, wf, wo, wz};
    const float* wg = wptr[gg] + (size_t)d*4096;
    float* outB = wt4 + (size_t)(gg*8 + d)*4096;
    for (int idx = tid; idx < 4096; idx += 256) {
      const int o = idx >> 6, i = idx & 63;
      outB[(size_t)(i >> 2)*256 + o*4 + (i & 3)] = wg[idx];
    }
    return;
  }
  const int row = bid - 2049;   // 0..4347
  if (row >= 4096) {
    const int idx = row - 4096;           // 0..251
    const int b = idx / 63, rr = idx % 63;
    const size_t base = ((size_t)(b*1087 + rr)) << 9;
    xpad[base + tid] = 0;
    xpad[base + tid + 256] = 0;
    return;
  }
  const int e0 = tid, e1 = tid + 256;
  const size_t ib = (size_t)row << 9;
  const float v0 = x[ib + e0], v1 = x[ib + e1];
  float a = v0 + v1, b2 = v0*v0 + v1*v1;
  blockReduce2(a, b2, (float*)tile);
  const float mu = a * (1.f/512.f);
  const float var = b2 * (1.f/512.f) - mu*mu;
  const float rs = rsqrtf(var + EPS);
  const int bb = row >> 10, t = row & 1023;
  const size_t ob = ((size_t)(bb*1087 + 63 + t)) << 9;
  xpad[ob + e0] = f2bf((v0 - mu) * rs * g[e0] + bta[e0]);
  xpad[ob + e1] = f2bf((v1 - mu) * rs * g[e1] + bta[e1]);
}

// ---- K3: conv-as-GEMM, 256x256 tile, BK=64, split-K=8, bf16 partials.
// R12-proven barrier-minimal tile schedule (unchanged).
__global__ __launch_bounds__(512) void k_gemm256(
    const u16* __restrict__ wt, const u16* __restrict__ xpad,
    u16* __restrict__ part, int kSteps)
{
  extern __shared__ __align__(16) char smem[];   // 2 x 65536
  const int tid  = threadIdx.x;
  const int lane = tid & 63;
  const int wid  = tid >> 6;
  const int wm = wid >> 2, wn = wid & 3;          // 2M x 4N waves, 128x64 out each
  const int mb = blockIdx.x, nb = blockIdx.y, sp = blockIdx.z;

  const int wmBase = wm * 128;
  const int wnBase = wn * 64;
  const int l15  = lane & 15;
  const int kb16 = (lane >> 4) << 4;

  const int srow = tid >> 3;
  const int scb  = (tid & 7) << 4;
  const int csrcE = (scb ^ ((srow & 7) << 4)) >> 1;   // pre-swizzled source col

  const u16* aB0;
  {
    const int m0 = mb*256 + srow;          // 256-chunks never cross a batch boundary
    const int b = m0 >> 10, t = m0 & 1023;
    aB0 = xpad + (((size_t)(b*1087 + t)) << 9) + csrcE;   // NO +63 (R8 bug)
  }
  const u16* bB0 = wt + (((size_t)(nb*256 + srow)) << 15) + csrcE;
  const size_t dst16 = (size_t)tid * 16;

  f32x4 acc[8][4];
  const f32x4 zero4 = {0.f, 0.f, 0.f, 0.f};
  #pragma unroll
  for (int i = 0; i < 8; ++i)
    #pragma unroll
    for (int j = 0; j < 4; ++j) acc[i][j] = zero4;

  const int kBase = sp * kSteps;

  auto STAGE = [&](int ktg, char* buf) {
    const size_t aOff = ((size_t)(ktg >> 3) << 9) + ((size_t)(ktg & 7) << 6);
    const size_t bOff = (size_t)ktg << 6;
    gload16(aB0 + aOff,                  buf + dst16);
    gload16(aB0 + (64ull << 9) + aOff,   buf +  8192 + dst16);
    gload16(aB0 + (128ull << 9) + aOff,  buf + 16384 + dst16);
    gload16(aB0 + (192ull << 9) + aOff,  buf + 24576 + dst16);
    gload16(bB0 + bOff,                   buf + 32768 + dst16);
    gload16(bB0 + (64ull << 15) + bOff,   buf + 40960 + dst16);
    gload16(bB0 + (128ull << 15) + bOff,  buf + 49152 + dst16);
    gload16(bB0 + (192ull << 15) + bOff,  buf + 57344 + dst16);
  };

  STAGE(kBase, smem);
  __syncthreads();

  for (int kt = 0; kt < kSteps; ++kt) {
    const char* curA = smem + (size_t)(kt & 1) * 65536;
    const char* curB = curA + 32768;
    char* nxt = smem + (size_t)((kt & 1) ^ 1) * 65536;
    if (kt + 1 < kSteps) STAGE(kBase + kt + 1, nxt);

    bf16x8 bv[4][2];
    #pragma unroll
    for (int nr = 0; nr < 4; ++nr) {
      const int r = wnBase + nr*16 + l15;
      const int sw = (r & 7) << 4;
      bv[nr][0] = *(const bf16x8*)(curB + r*128 + ((kb16     ) ^ sw));
      bv[nr][1] = *(const bf16x8*)(curB + r*128 + ((kb16 + 64) ^ sw));
    }
    #pragma unroll
    for (int q = 0; q < 4; ++q) {
      bf16x8 af0, af0b, af1, af1b;
      { const int r = wmBase + q*32 + l15; const int sw = (r & 7) << 4;
        af0  = *(const bf16x8*)(curA + r*128 + ((kb16     ) ^ sw));
        af0b = *(const bf16x8*)(curA + r*128 + ((kb16 + 64) ^ sw)); }
      { const int r = wmBase + q*32 + 16 + l15; const int sw = (r & 7) << 4;
        af1  = *(const bf16x8*)(curA + r*128 + ((kb16     ) ^ sw));
        af1b = *(const bf16x8*)(curA + r*128 + ((kb16 + 64) ^ sw)); }
      #pragma unroll
      for (int nr = 0; nr < 4; ++nr) {
        acc[2*q][nr]   = __builtin_amdgcn_mfma_f32_16x16x32_bf16(af0,  bv[nr][0], acc[2*q][nr],   0, 0, 0);
        acc[2*q][nr]   = __builtin_amdgcn_mfma_f32_16x16x32_bf16(af0b, bv[nr][1], acc[2*q][nr],   0, 0, 0);
        acc[2*q+1][nr] = __builtin_amdgcn_mfma_f32_16x16x32_bf16(af1,  bv[nr][0], acc[2*q+1][nr], 0, 0, 0);
        acc[2*q+1][nr] = __builtin_amdgcn_mfma_f32_16x16x32_bf16(af1b, bv[nr][1], acc[2*q+1][nr], 0, 0, 0);
      }
    }
    __syncthreads();
  }

  u16* outp = part + (size_t)sp * 4096 * 512;
  #pragma unroll
  for (int mr = 0; mr < 8; ++mr)
    #pragma unroll
    for (int nr = 0; nr < 4; ++nr)
      #pragma unroll
      for (int r4 = 0; r4 < 4; ++r4) {
        const int row = mb*256 + wmBase + mr*16 + ((lane >> 4) << 2) + r4;
        const int col = nb*256 + wnBase + nr*16 + l15;
        outp[((size_t)row << 9) + col] = f2bf(acc[mr][nr][r4]);
      }
}

// ---- K3 (fallback): R10-proven 128x128 tile, static 32KB LDS (bf16 partials).
__global__ __launch_bounds__(512) void k_gemm128(
    const u16* __restrict__ wt, const u16* __restrict__ xpad,
    u16* __restrict__ part, int kSteps)
{
  __shared__ __align__(16) u16 lsA[128*64];
  __shared__ __align__(16) u16 lsB[128*64];
  const int tid  = threadIdx.x;
  const int lane = tid & 63;
  const int wid  = tid >> 6;
  const int wm = wid >> 2, wn = wid & 3;
  const int mb = blockIdx.x, nb = blockIdx.y, sp = blockIdx.z;

  const int srow = tid >> 3;
  const int scb  = (tid & 7) << 4;
  const int csrcE = (scb ^ ((srow & 7) << 4)) >> 1;

  const int m0 = mb*128 + srow, m1 = m0 + 64;
  const int b0 = m0 >> 10, t0 = m0 & 1023;
  const int b1 = m1 >> 10, t1 = m1 & 1023;
  const u16* aB0 = xpad + (((size_t)(b0*1087 + t0)) << 9) + csrcE;
  const u16* aB1 = xpad + (((size_t)(b1*1087 + t1)) << 9) + csrcE;
  const u16* bB0 = wt + (((size_t)(nb*128 + srow)) << 15) + csrcE;
  const u16* bB1 = wt + (((size_t)(nb*128 + srow + 64)) << 15) + csrcE;
  u16* dA0 = &lsA[tid*8]; u16* dA1 = &lsA[4096 + tid*8];
  u16* dB0 = &lsB[tid*8]; u16* dB1 = &lsB[4096 + tid*8];

  const f32x4 zero4 = {0.f, 0.f, 0.f, 0.f};
  f32x4 acc[4][2];
  #pragma unroll
  for (int i = 0; i < 4; ++i)
    #pragma unroll
    for (int j = 0; j < 2; ++j) acc[i][j] = zero4;

  const int kBase = sp * kSteps;
  for (int kt = 0; kt < kSteps; ++kt) {
    const int ktg = kBase + kt;
    const int k  = ktg >> 3;
    const int i0 = (ktg & 7) << 6;
    const int aStep = (k << 9) + i0;
    gload16(aB0 + aStep, dA0);
    gload16(aB1 + aStep, dA1);
    gload16(bB0 + ((size_t)ktg << 6), dB0);
    gload16(bB1 + ((size_t)ktg << 6), dB1);
    __syncthreads();
    #pragma unroll
    for (int ks = 0; ks < 2; ++ks) {
      bf16x8 af[4], bv[2];
      #pragma unroll
      for (int mr = 0; mr < 4; ++mr) {
        const int r  = wm*64 + mr*16 + (lane & 15);
        const int cb = (ks << 6) + ((lane >> 4) << 4);
        af[mr] = *(const bf16x8*)((const char*)lsA + (r*128 + (cb ^ ((r & 7) << 4))));
      }
      #pragma unroll
      for (int nr = 0; nr < 2; ++nr) {
        const int r  = wn*32 + nr*16 + (lane & 15);
        const int cb = (ks << 6) + ((lane >> 4) << 4);
        bv[nr] = *(const bf16x8*)((const char*)lsB + (r*128 + (cb ^ ((r & 7) << 4))));
      }
      #pragma unroll
      for (int mr = 0; mr < 4; ++mr)
        #pragma unroll
        for (int nr = 0; nr < 2; ++nr)
          acc[mr][nr] = __builtin_amdgcn_mfma_f32_16x16x32_bf16(af[mr], bv[nr], acc[mr][nr], 0, 0, 0);
    }
    __syncthreads();
  }

  u16* outp = part + (size_t)sp * 4096 * 512;
  #pragma unroll
  for (int mr = 0; mr < 4; ++mr)
    #pragma unroll
    for (int nr = 0; nr < 2; ++nr)
      #pragma unroll
      for (int r4 = 0; r4 < 4; ++r4) {
        const int row = mb*128 + wm*64 + mr*16 + ((lane >> 4) << 2) + r4;
        const int col = nb*128 + wn*32 + nr*16 + (lane & 15);
        outp[((size_t)row << 9) + col] = f2bf(acc[mr][nr][r4]);
      }
}

// ---- K5: fused fp32 block-diag gates + LNs + gating + ct/nt partials.
// R17 dbuf staging + coalesced wt4 weight reads (lane-consecutive float4).
__global__ __launch_bounds__(512, 2) void k_bdg3(
    const u16* __restrict__ part, int S,
    const float* __restrict__ cb, const u16* __restrict__ xpad,
    const float* __restrict__ wt4,
    const float* __restrict__ bi, const float* __restrict__ bf_,
    const float* __restrict__ bo, const float* __restrict__ bz,
    const float* __restrict__ rv,
    const float* __restrict__ lnig, const float* __restrict__ lnib,
    const float* __restrict__ lnfg, const float* __restrict__ lnfb,
    const float* __restrict__ lnog, const float* __restrict__ lnob,
    const float* __restrict__ lnzg, const float* __restrict__ lnzb,
    const float* __restrict__ lncg, const float* __restrict__ lncb,
    const float* __restrict__ lnng, const float* __restrict__ lnnb,
    const float* __restrict__ mt1, const float* __restrict__ ct1,
    const float* __restrict__ nt1,
    float* __restrict__ obuf, float* __restrict__ pct, float* __restrict__ pnt)
{
  extern __shared__ char smem2[];
  float* pre4 = (float*)smem2;                 // [4][16][512] f32 = 131072 B
  float* xbuf = (float*)(smem2 + 131072);      // [2][2][16][68] dbuf (17408 B)
  float* pctW = pre4;                          // [8][512] phase-2 reuse
  float* pntW = pre4 + 8*512;

  const int tid  = threadIdx.x;
  const int lane = tid & 63;
  const int w    = tid >> 6;
  const int g    = w >> 1;
  const int rh   = w & 1;
  const int rowBase = blockIdx.x * 16;
  const size_t N = 4096ull*512;
  const float* bptr[4] = {bi, bf_, bo, bz};
  const float* bg = bptr[g];

  const int sr    = tid >> 5;          // staging row 0..15
  const int scol2 = (tid & 31) << 1;   // staging col pair

  auto STAGEX = [&](int d, int b) {
    float* xsc = xbuf + (size_t)b * 2*16*68;
    float* xsl = xsc + 16*68;
    const int row = rowBase + sr, col = d*64 + scol2;
    float v0 = cb[col], v1 = cb[col+1];
    for (int s = 0; s < S; ++s) {
      const u32 p = *(const u32*)&part[(size_t)s*N + (size_t)row*512 + col];
      v0 += bf2f((u16)p);
      v1 += bf2f((u16)(p >> 16));
    }
    xsc[sr*68 + scol2]     = v0 / (1.f + expf(-v0));
    xsc[sr*68 + scol2 + 1] = v1 / (1.f + expf(-v1));
    const int bq = row >> 10, tt = row & 1023;
    const u32 xp = *(const u32*)&xpad[(((size_t)(bq*1087 + 63 + tt)) << 9) + col];
    xsl[sr*68 + scol2]     = bf2f((u16)xp);
    xsl[sr*68 + scol2 + 1] = bf2f((u16)(xp >> 16));
  };

  STAGEX(0, 0);
  __syncthreads();

  for (int d = 0; d < 8; ++d) {
    if (d + 1 < 8) STAGEX(d + 1, (d + 1) & 1);   // writes other buffer

    float4 wreg[16];
    {
      const float* wb = wt4 + (size_t)(g*8 + d)*4096 + lane*4;
      #pragma unroll
      for (int j = 0; j < 16; ++j) wreg[j] = *(const float4*)(wb + (size_t)j*256);
    }

    const float* xsc = xbuf + (size_t)(d & 1) * 2*16*68;
    const float* X = (g < 2) ? xsc : (xsc + 16*68);
    float acc[8];
    #pragma unroll
    for (int r8 = 0; r8 < 8; ++r8) acc[r8] = 0.f;
    #pragma unroll
    for (int i4 = 0; i4 < 16; ++i4) {
      const float4 wv = wreg[i4];
      #pragma unroll
      for (int r8 = 0; r8 < 8; ++r8) {
        const float4 xv = *(const float4*)(X + (rh*8 + r8)*68 + (i4 << 2));
        acc[r8] = fmaf(xv.w, wv.w, fmaf(xv.z, wv.z, fmaf(xv.y, wv.y, fmaf(xv.x, wv.x, acc[r8]))));
      }
    }
    const int e = d*64 + lane;
    const float bias = bg[e] + rv[g*512 + e];
    #pragma unroll
    for (int r8 = 0; r8 < 8; ++r8)
      pre4[(g*16 + rh*8 + r8)*512 + e] = acc[r8] + bias;

    __syncthreads();   // next-iter buffer staged; this-iter reads complete
  }

  // phase 2 (R14-exact)
  float pcA[8], pnA[8];
  #pragma unroll
  for (int j = 0; j < 8; ++j) { pcA[j] = 0.f; pnA[j] = 0.f; }
  for (int rr = 0; rr < 2; ++rr) {
    const int prow = 2*w + rr;
    const int grow = rowBase + prow;
    float gi[8], gf[8], go_[8], gz[8];
    #pragma unroll
    for (int j = 0; j < 8; ++j) {
      const int c = lane + 64*j;
      gi[j]  = pre4[(0*16 + prow)*512 + c];
      gf[j]  = pre4[(1*16 + prow)*512 + c];
      go_[j] = pre4[(2*16 + prow)*512 + c];
      gz[j]  = pre4[(3*16 + prow)*512 + c];
    }
    float si=0,si2=0,sf=0,sf2=0,so=0,so2=0,sz=0,sz2=0;
    #pragma unroll
    for (int j = 0; j < 8; ++j) {
      si += gi[j];  si2 += gi[j]*gi[j];
      sf += gf[j];  sf2 += gf[j]*gf[j];
      so += go_[j]; so2 += go_[j]*go_[j];
      sz += gz[j];  sz2 += gz[j]*gz[j];
    }
    red64_2(si, si2); red64_2(sf, sf2); red64_2(so, so2); red64_2(sz, sz2);
    const float mui = si*(1.f/512.f), rsi = rsqrtf(si2*(1.f/512.f) - mui*mui + EPS);
    const float muf = sf*(1.f/512.f), rsf = rsqrtf(sf2*(1.f/512.f) - muf*muf + EPS);
    const float muo = so*(1.f/512.f), rso = rsqrtf(so2*(1.f/512.f) - muo*muo + EPS);
    const float muz = sz*(1.f/512.f), rsz = rsqrtf(sz2*(1.f/512.f) - muz*muz + EPS);

    float ctv[8], ntv[8];
    float cS=0,cS2=0,nS=0,nS2=0;
    #pragma unroll
    for (int j = 0; j < 8; ++j) {
      const int c = lane + 64*j;
      const float li = (gi[j]-mui)*rsi*lnig[c] + lnib[c];
      const float lf = (gf[j]-muf)*rsf*lnfg[c] + lnfb[c];
      const float ov = 1.f/(1.f+expf(-((go_[j]-muo)*rso*lnog[c] + lnob[c])));
      const float zv = tanhf((gz[j]-muz)*rsz*lnzg[c] + lnzb[c]);
      obuf[(size_t)grow*512 + c] = ov;
      const float lfm = lf + mt1[c];
      const float mm = fmaxf(lfm, li);
      const float iv = expf(li - mm), fv = expf(lfm - mm);
      ctv[j] = fv*ct1[c] + iv*zv;
      ntv[j] = fv*nt1[c] + iv;
      cS += ctv[j]; cS2 += ctv[j]*ctv[j];
      nS += ntv[j]; nS2 += ntv[j]*ntv[j];
    }
    red64_2(cS, cS2); red64_2(nS, nS2);
    const float muc = cS*(1.f/512.f), rsc = rsqrtf(cS2*(1.f/512.f) - muc*muc + EPS);
    const float mun = nS*(1.f/512.f), rsn = rsqrtf(nS2*(1.f/512.f) - mun*mun + EPS);
    #pragma unroll
    for (int j = 0; j < 8; ++j) {
      const int c = lane + 64*j;
      pcA[j] += (ctv[j]-muc)*rsc*lncg[c] + lncb[c];
      pnA[j] += (ntv[j]-mun)*rsn*lnng[c] + lnnb[c];
    }
  }
  __syncthreads();
  #pragma unroll
  for (int j = 0; j < 8; ++j) {
    const int c = lane + 64*j;
    pctW[w*512 + c] = pcA[j];
    pntW[w*512 + c] = pnA[j];
  }
  __syncthreads();
  {
    const int e = tid;
    float cs = 0.f, ns = 0.f;
    #pragma unroll
    for (int ww = 0; ww < 8; ++ww) { cs += pctW[ww*512 + e]; ns += pntW[ww*512 + e]; }
    pct[(size_t)blockIdx.x*512 + e] = cs;
    pnt[(size_t)blockIdx.x*512 + e] = ns;
  }
}

// ---- K5b: r[e] = sum_b(pct)/sum_b(pnt) over 256 partials; 512 blocks x 256 thr
__global__ void k_r(const float* __restrict__ pct, const float* __restrict__ pnt,
                    float* __restrict__ rout) {
  __shared__ float sm[8];
  const int e = blockIdx.x, tid = threadIdx.x;
  float cs = pct[(size_t)tid*512 + e];
  float ns = pnt[(size_t)tid*512 + e];
  blockReduce2(cs, ns, sm);
  if (tid == 0) rout[e] = cs / ns;
}

// ---- K6: ht-row LN accumulation, wave-per-row (256 blocks x 16 rows)
__global__ __launch_bounds__(256) void k_ht(
    const float* __restrict__ obuf, const float* __restrict__ r,
    const float* __restrict__ lnhg, const float* __restrict__ lnhb,
    float* __restrict__ phtPart)
{
  __shared__ float rsh[512];
  __shared__ float phtW[4][512];
  const int tid = threadIdx.x, lane = tid & 63, w = tid >> 6;
  rsh[tid] = r[tid]; rsh[tid + 256] = r[tid + 256];
  __syncthreads();
  float accH[8] = {0,0,0,0,0,0,0,0};
  const int rowBase = blockIdx.x * 16;
  for (int rr = 0; rr < 4; ++rr) {
    const int row = rowBase + w*4 + rr;
    float v[8], s = 0.f, s2 = 0.f;
    #pragma unroll
    for (int j = 0; j < 8; ++j) {
      const int c = lane + 64*j;
      v[j] = obuf[(size_t)row*512 + c] * rsh[c];
      s += v[j]; s2 += v[j]*v[j];
    }
    #pragma unroll
    for (int m = 1; m <= 32; m <<= 1) { s += __shfl_xor(s, m); s2 += __shfl_xor(s2, m); }
    const float mu = s*(1.f/512.f), rs = rsqrtf(s2*(1.f/512.f) - mu*mu + EPS);
    #pragma unroll
    for (int j = 0; j < 8; ++j) {
      const int c = lane + 64*j;
      accH[j] += (v[j]-mu)*rs*lnhg[c] + lnhb[c];
    }
  }
  #pragma unroll
  for (int j = 0; j < 8; ++j) phtW[w][lane + 64*j] = accH[j];
  __syncthreads();
  const int e0 = tid, e1 = tid + 256;
  float h0 = 0.f, h1 = 0.f;
  #pragma unroll
  for (int ww = 0; ww < 4; ++ww) { h0 += phtW[ww][e0]; h1 += phtW[ww][e1]; }
  phtPart[(size_t)blockIdx.x*512 + e0] = h0;
  phtPart[(size_t)blockIdx.x*512 + e1] = h1;
}

// ---- K6b: htm[e] = (sum_b pht[b][e]) / 4096; 512 blocks x 256 thr
__global__ void k_hm(const float* __restrict__ pht, float* __restrict__ hm) {
  __shared__ float sm[8];
  const int e = blockIdx.x, tid = threadIdx.x;
  float v = pht[(size_t)tid*512 + e];
  float d = 0.f;
  blockReduce2(v, d, sm);
  if (tid == 0) hm[e] = v * (1.f/4096.f);
}

// ---- K7: fused gn-LN + left/right GEMV + gelu; 682 blocks x 64.
__global__ void k_lr2(const float* __restrict__ hm,
                      const float* __restrict__ gng, const float* __restrict__ gnb,
                      const float* __restrict__ lw, const float* __restrict__ lb,
                      const float* __restrict__ rw, const float* __restrict__ rb_,
                      float* __restrict__ lr) {
  const int j = blockIdx.x, lane = threadIdx.x;
  float h[8];
  float a = 0.f, b2 = 0.f;
  #pragma unroll
  for (int q = 0; q < 8; ++q) {
    h[q] = hm[lane + 64*q];
    a += h[q]; b2 += h[q]*h[q];
  }
  red64_2(a, b2);
  const float mu = a*(1.f/512.f), rs = rsqrtf(b2*(1.f/512.f) - mu*mu + EPS);
  const float* lwp = lw + (size_t)j*512;
  const float* rwp = rw + (size_t)j*512;
  float dl = 0.f, dr = 0.f;
  #pragma unroll
  for (int q = 0; q < 8; ++q) {
    const int e = lane + 64*q;
    const float sv = (h[q]-mu)*rs*gng[e] + gnb[e];
    dl = fmaf(lwp[e], sv, dl);
    dr = fmaf(rwp[e], sv, dr);
  }
  #pragma unroll
  for (int off = 32; off > 0; off >>= 1) { dl += __shfl_down(dl, off); dr += __shfl_down(dr, off); }
  if (lane == 0) {
    const float L = dl + lb[j];
    const float R = dr + rb_[j];
    const float gelu = 0.5f*R*(1.f + erff(R*0.70710678118654752440f));
    lr[j] = L * gelu;
  }
}

// ---- K8: fused LN(lr) + proj: 512 blocks x 64 lanes
__global__ void k_projln(const float* __restrict__ lr,
                         const float* __restrict__ og, const float* __restrict__ ob,
                         const float* __restrict__ pw, const float* __restrict__ pb,
                         float* __restrict__ out) {
  const int e = blockIdx.x, lane = threadIdx.x;
  float lv[11];
  float a = 0.f, b2 = 0.f;
  #pragma unroll
  for (int q = 0; q < 11; ++q) {
    const int j = lane + 64*q;
    const float v = (j < 682) ? lr[j] : 0.f;
    lv[q] = v;
    a += v; b2 += v*v;
  }
  red64_2(a, b2);
  const float mu = a*(1.f/682.f), rs = rsqrtf(b2*(1.f/682.f) - mu*mu + EPS);
  const float* wp = pw + (size_t)e*682;
  float s = 0.f;
  #pragma unroll
  for (int q = 0; q < 11; ++q) {
    const int j = lane + 64*q;
    if (j < 682) s = fmaf((lv[q]-mu)*rs*og[j] + ob[j], wp[j], s);
  }
  #pragma unroll
  for (int off = 32; off > 0; off >>= 1) s += __shfl_down(s, off);
  if (lane == 0) out[e] = s + pb[e];
}

extern "C" void kernel_launch(void* const* d_in, const int* in_sizes, int n_in,
                              void* d_out, int out_size, void* d_ws, size_t ws_size,
                              hipStream_t stream) {
  const float* x      = (const float*)d_in[0];
  const float* conv_w = (const float*)d_in[1];
  const float* conv_b = (const float*)d_in[2];
  const float* wi  = (const float*)d_in[3];
  const float* wf  = (const float*)d_in[4];
  const float* wo  = (const float*)d_in[5];
  const float* wz  = (const float*)d_in[6];
  const float* rwi = (const float*)d_in[7];
  const float* rwf = (const float*)d_in[8];
  const float* rwo = (const float*)d_in[9];
  const float* rwz = (const float*)d_in[10];
  const float* bi  = (const float*)d_in[11];
  const float* bf  = (const float*)d_in[12];
  const float* bo  = (const float*)d_in[13];
  const float* bz  = (const float*)d_in[14];
  const float* ln_g  = (const float*)d_in[15];
  const float* ln_b  = (const float*)d_in[16];
  const float* lni_g = (const float*)d_in[17];
  const float* lni_b = (const float*)d_in[18];
  const float* lnf_g = (const float*)d_in[19];
  const float* lnf_b = (const float*)d_in[20];
  const float* lno_g = (const float*)d_in[21];
  const float* lno_b = (const float*)d_in[22];
  const float* lnz_g = (const float*)d_in[23];
  const float* lnz_b = (const float*)d_in[24];
  const float* gn_g  = (const float*)d_in[25];
  const float* gn_b  = (const float*)d_in[26];
  const float* lnc_g = (const float*)d_in[27];
  const float* lnc_b = (const float*)d_in[28];
  const float* lnn_g = (const float*)d_in[29];
  const float* lnn_b = (const float*)d_in[30];
  const float* lnh_g = (const float*)d_in[31];
  const float* lnh_b = (const float*)d_in[32];
  const float* left_w  = (const float*)d_in[33];
  const float* left_b  = (const float*)d_in[34];
  const float* right_w = (const float*)d_in[35];
  const float* right_b = (const float*)d_in[36];
  const float* lnout_g = (const float*)d_in[37];
  const float* lnout_b = (const float*)d_in[38];
  const float* proj_w  = (const float*)d_in[39];
  const float* proj_b  = (const float*)d_in[40];
  const float* nt1 = (const float*)d_in[41];
  const float* ct1 = (const float*)d_in[42];
  const float* ht1 = (const float*)d_in[43];
  const float* mt1 = (const float*)d_in[44];
  float* dout = (float*)d_out;

  char* ws = (char*)d_ws;
  size_t off = 0;
  auto alloc = [&](size_t n) { size_t o = off; off += (n + 255) & ~(size_t)255; return o; };

  const size_t SZ_WT   = 512ull*32768*2;   // 32 MB
  const size_t SZ_XPAD = 4ull*1087*512*2;  // 4.45 MB
  const size_t SZ_PART = 4096ull*512*2;    // 4 MB per split (bf16)
  const size_t SZ_OBUF = 4096ull*512*4;    // 8 MB
  const size_t SZ_WT4  = 4ull*512*512*4;   // 4 MB transposed gate weights
  const size_t tail = SZ_OBUF + SZ_WT4 + 3*(256*512*4 + 256) + 6*4096;

  int S;
  bool use256;
  if (SZ_WT + SZ_XPAD + 8*SZ_PART + tail + 65536 <= ws_size) { S = 8; use256 = true; }
  else if (SZ_WT + SZ_XPAD + 4*SZ_PART + tail + 65536 <= ws_size) { S = 4; use256 = false; }
  else { S = 2; use256 = false; }

  const size_t o_wt   = alloc(SZ_WT);
  const size_t o_xpad = alloc(SZ_XPAD);
  const size_t o_part = alloc((size_t)S * SZ_PART);
  const size_t o_obuf = alloc(SZ_OBUF);
  const size_t o_wt4  = alloc(SZ_WT4);
  const size_t o_rv   = alloc(4*512*4);
  const size_t o_pct  = alloc(256*512*4);
  const size_t o_pnt  = alloc(256*512*4);
  const size_t o_pht  = alloc(256*512*4);
  const size_t o_r    = alloc(512*4);
  const size_t o_hm   = alloc(512*4);
  const size_t o_lr   = alloc(682*4);

  u16*   wt    = (u16*)(ws + o_wt);
  u16*   xpad  = (u16*)(ws + o_xpad);
  u16*   part  = (u16*)(ws + o_part);
  float* obuf  = (float*)(ws + o_obuf);
  float* wt4   = (float*)(ws + o_wt4);
  float* rv    = (float*)(ws + o_rv);
  float* pct   = (float*)(ws + o_pct);
  float* pnt   = (float*)(ws + o_pnt);
  float* pht   = (float*)(ws + o_pht);
  float* rbuf  = (float*)(ws + o_r);
  float* hmbuf = (float*)(ws + o_hm);
  float* lrbuf = (float*)(ws + o_lr);

  const int bdgLds = 4*16*512*4 + 2*2*16*68*4;   // 148480 B
  (void)hipFuncSetAttribute((const void*)k_bdg3, hipFuncAttributeMaxDynamicSharedMemorySize, bdgLds);

  k_prep<<<6429, 256, 0, stream>>>(conv_w, wt, rwi, rwf, rwo, rwz, ht1, rv,
                                   x, ln_g, ln_b, xpad,
                                   wi, wf, wo, wz, wt4);
  if (use256) {
    const int gemmLds = 2 * 65536;             // 128 KiB double buffer
    (void)hipFuncSetAttribute((const void*)k_gemm256, hipFuncAttributeMaxDynamicSharedMemorySize, gemmLds);
    k_gemm256<<<dim3(16, 2, 8), 512, gemmLds, stream>>>(wt, xpad, part, 512 / 8);
  } else {
    k_gemm128<<<dim3(32, 4, S), 512, 0, stream>>>(wt, xpad, part, 512 / S);
  }
  k_bdg3<<<256, 512, bdgLds, stream>>>(part, S, conv_b, xpad,
      wt4, bi, bf, bo, bz, rv,
      lni_g, lni_b, lnf_g, lnf_b, lno_g, lno_b, lnz_g, lnz_b,
      lnc_g, lnc_b, lnn_g, lnn_b, mt1, ct1, nt1,
      obuf, pct, pnt);
  k_r<<<512, 256, 0, stream>>>(pct, pnt, rbuf);
  k_ht<<<256, 256, 0, stream>>>(obuf, rbuf, lnh_g, lnh_b, pht);
  k_hm<<<512, 256, 0, stream>>>(pht, hmbuf);
  k_lr2<<<682, 64, 0, stream>>>(hmbuf, gn_g, gn_b,
      left_w, left_b, right_w, right_b, lrbuf);
  k_projln<<<512, 64, 0, stream>>>(lrbuf, lnout_g, lnout_b, proj_w, proj_b, dout);
}